// Round 7
// baseline (3044.388 us; speedup 1.0000x reference)
//
#include <hip/hip_runtime.h>
#include <math.h>

#define N_USERS    50000
#define N_ENTITIES 100000
#define N_NODES    150000
#define N_EDGES    3000000
#define BATCH      8192
#define SLOPE      0.2f
#define EPSF       1e-12f

// bucket partition: bucket = h>>6 (64 nodes per bucket)
#define NBUK   2344            // ceil(150000/64)
#define CAP    1536            // per-bucket record capacity (mean 1280, sd 36: +7.1 sd)
#define BLK_E  32768           // edges per partition block
#define NPB    ((N_EDGES + BLK_E - 1) / BLK_E)   // 92

// ---------------------------------------------------------------------------
// partition_k: single-pass bucket scatter.
// Record: int2 { t | (h&63)<<18 , bitcast(a) }.  Per-(block,bucket) windows
// are contiguous (claimed via one atomicAdd per bucket per block), so cache
// lines have a single writer -> no write-allocate amplification.
// ---------------------------------------------------------------------------
__global__ __launch_bounds__(256)
void partition_k(const int* __restrict__ all_h, const int* __restrict__ all_t,
                 const float* __restrict__ A,
                 int* __restrict__ gcursor, int2* __restrict__ rec) {
    __shared__ int hist[NBUK];
    __shared__ int base[NBUK];
    __shared__ int cnt2[NBUK];
    int t = threadIdx.x;
    for (int i = t; i < NBUK; i += 256) { hist[i] = 0; cnt2[i] = 0; }
    __syncthreads();

    int e0 = blockIdx.x * BLK_E;
    int e1 = e0 + BLK_E; if (e1 > N_EDGES) e1 = N_EDGES;

    for (int e = e0 + t; e < e1; e += 256)
        atomicAdd(&hist[all_h[e] >> 6], 1);
    __syncthreads();

    for (int i = t; i < NBUK; i += 256)
        base[i] = hist[i] ? atomicAdd(&gcursor[i], hist[i]) : 0;
    __syncthreads();

    for (int e = e0 + t; e < e1; e += 256) {
        int h = all_h[e];
        int b = h >> 6;
        int r = base[b] + atomicAdd(&cnt2[b], 1);
        if (r < CAP)   // never trips (7+ sigma margin); guards OOB
            rec[(size_t)b * CAP + r] =
                make_int2(all_t[e] | ((h & 63) << 18), __float_as_int(A[e]));
    }
}

// ---------------------------------------------------------------------------
// bucket_side_k: one block per bucket. Zero a 64xD LDS tile, stream the
// bucket's records (coalesced), gather ego[t] rows, LDS-atomicAdd into the
// tile, then write side rows coalesced.
// ---------------------------------------------------------------------------
template<int D, bool CONCAT>
__global__ __launch_bounds__(256)
void bucket_side_k(const int* __restrict__ gcursor, const int2* __restrict__ rec,
                   const float* __restrict__ ego_in,
                   const float* __restrict__ user_emb, const float* __restrict__ ent_emb,
                   float* __restrict__ side) {
    __shared__ float tile[64 * D];
    int t = threadIdx.x;
    #pragma unroll
    for (int i = t; i < 64 * D; i += 256) tile[i] = 0.f;
    __syncthreads();

    int b = blockIdx.x;
    int cnt = gcursor[b]; if (cnt > CAP) cnt = CAP;
    const int2* r = rec + (size_t)b * CAP;
    int w = t >> 6, lane = t & 63;
    int s = (w * cnt) >> 2, e = ((w + 1) * cnt) >> 2;

    #define ROW64(tt) (CONCAT ? (((tt) < N_USERS) ? (user_emb + (size_t)(tt) * 64) \
                                                  : (ent_emb + (size_t)((tt) - N_USERS) * 64)) \
                              : (ego_in + (size_t)(tt) * 64))
    if (D == 64) {
        int i = s;
        for (; i + 8 <= e; i += 8) {
            int2 p0 = r[i + 0]; int2 p1 = r[i + 1];
            int2 p2 = r[i + 2]; int2 p3 = r[i + 3];
            int2 p4 = r[i + 4]; int2 p5 = r[i + 5];
            int2 p6 = r[i + 6]; int2 p7 = r[i + 7];
            float x0 = ROW64(p0.x & 0x3FFFF)[lane];
            float x1 = ROW64(p1.x & 0x3FFFF)[lane];
            float x2 = ROW64(p2.x & 0x3FFFF)[lane];
            float x3 = ROW64(p3.x & 0x3FFFF)[lane];
            float x4 = ROW64(p4.x & 0x3FFFF)[lane];
            float x5 = ROW64(p5.x & 0x3FFFF)[lane];
            float x6 = ROW64(p6.x & 0x3FFFF)[lane];
            float x7 = ROW64(p7.x & 0x3FFFF)[lane];
            atomicAdd(&tile[((p0.x >> 18) & 63) * 64 + lane], __int_as_float(p0.y) * x0);
            atomicAdd(&tile[((p1.x >> 18) & 63) * 64 + lane], __int_as_float(p1.y) * x1);
            atomicAdd(&tile[((p2.x >> 18) & 63) * 64 + lane], __int_as_float(p2.y) * x2);
            atomicAdd(&tile[((p3.x >> 18) & 63) * 64 + lane], __int_as_float(p3.y) * x3);
            atomicAdd(&tile[((p4.x >> 18) & 63) * 64 + lane], __int_as_float(p4.y) * x4);
            atomicAdd(&tile[((p5.x >> 18) & 63) * 64 + lane], __int_as_float(p5.y) * x5);
            atomicAdd(&tile[((p6.x >> 18) & 63) * 64 + lane], __int_as_float(p6.y) * x6);
            atomicAdd(&tile[((p7.x >> 18) & 63) * 64 + lane], __int_as_float(p7.y) * x7);
        }
        for (; i < e; ++i) {
            int2 p = r[i];
            float x = ROW64(p.x & 0x3FFFF)[lane];
            atomicAdd(&tile[((p.x >> 18) & 63) * 64 + lane], __int_as_float(p.y) * x);
        }
    } else {  // D == 32: two half-waves take alternating records
        int col = lane & 31;
        int half = lane >> 5;
        int i = s + half;
        for (; i + 6 < e; i += 8) {
            int2 p0 = r[i + 0]; int2 p1 = r[i + 2];
            int2 p2 = r[i + 4]; int2 p3 = r[i + 6];
            float x0 = ego_in[(size_t)(p0.x & 0x3FFFF) * 32 + col];
            float x1 = ego_in[(size_t)(p1.x & 0x3FFFF) * 32 + col];
            float x2 = ego_in[(size_t)(p2.x & 0x3FFFF) * 32 + col];
            float x3 = ego_in[(size_t)(p3.x & 0x3FFFF) * 32 + col];
            atomicAdd(&tile[((p0.x >> 18) & 63) * 32 + col], __int_as_float(p0.y) * x0);
            atomicAdd(&tile[((p1.x >> 18) & 63) * 32 + col], __int_as_float(p1.y) * x1);
            atomicAdd(&tile[((p2.x >> 18) & 63) * 32 + col], __int_as_float(p2.y) * x2);
            atomicAdd(&tile[((p3.x >> 18) & 63) * 32 + col], __int_as_float(p3.y) * x3);
        }
        for (; i < e; i += 2) {
            int2 p = r[i];
            float x = ego_in[(size_t)(p.x & 0x3FFFF) * 32 + col];
            atomicAdd(&tile[((p.x >> 18) & 63) * 32 + col], __int_as_float(p.y) * x);
        }
    }
    #undef ROW64
    __syncthreads();

    // write out tile rows (coalesced); last bucket is partial
    int nrows = N_NODES - b * 64; if (nrows > 64) nrows = 64;
    float* dst = side + (size_t)b * 64 * D;
    for (int i = t * 4; i < nrows * D; i += 1024)
        *(float4*)&dst[i] = *(const float4*)&tile[i];
}

// ---------------------------------------------------------------------------
// transform_k: tiled vector GEMM over node rows (unchanged from R6).
// ---------------------------------------------------------------------------
template<int DIN, int DOUT, int TILE_ROWS, bool CONCAT>
__global__ __launch_bounds__(256)
void transform_k(const float* __restrict__ ego_in,
                 const float* __restrict__ user_emb, const float* __restrict__ ent_emb,
                 const float* __restrict__ side,
                 const float* __restrict__ Wgc, const float* __restrict__ bgc,
                 const float* __restrict__ Wbi, const float* __restrict__ bbi,
                 float* __restrict__ ego_out) {
    constexpr int NG = DOUT / 8;
    constexpr int RG = 256 / NG;
    constexpr int RT = TILE_ROWS / RG;
    constexpr int STRIDE = DIN + 4;
    constexpr int KC = DIN / 4;

    __shared__ float sWgc[DIN * DOUT], sWbi[DIN * DOUT];
    __shared__ float sU[TILE_ROWS * STRIDE], sV[TILE_ROWS * STRIDE];

    int t = threadIdx.x;

    for (int i = t * 4; i < DIN * DOUT; i += 1024) {
        *(float4*)&sWgc[i] = *(const float4*)&Wgc[i];
        *(float4*)&sWbi[i] = *(const float4*)&Wbi[i];
    }

    int base = blockIdx.x * TILE_ROWS;
    for (int f = t; f < TILE_ROWS * KC; f += 256) {
        int row = f / KC, kc = f % KC;
        int n = base + row;
        int nc = n < N_NODES ? n : N_NODES - 1;
        const float* erow;
        if (CONCAT) {
            erow = (nc < N_USERS) ? user_emb + (size_t)nc * 64
                                  : ent_emb + (size_t)(nc - N_USERS) * 64;
        } else {
            erow = ego_in + (size_t)nc * DIN;
        }
        float4 e4 = ((const float4*)erow)[kc];
        float4 s4 = ((const float4*)(side + (size_t)nc * DIN))[kc];
        float4 u4, v4;
        u4.x = e4.x + s4.x; u4.y = e4.y + s4.y; u4.z = e4.z + s4.z; u4.w = e4.w + s4.w;
        v4.x = e4.x * s4.x; v4.y = e4.y * s4.y; v4.z = e4.z * s4.z; v4.w = e4.w * s4.w;
        *(float4*)&sU[row * STRIDE + kc * 4] = u4;
        *(float4*)&sV[row * STRIDE + kc * 4] = v4;
    }
    __syncthreads();

    int cg = t % NG, rg = t / NG;
    int c0 = cg * 8;
    int r0 = rg * RT;

    float accg[RT][8], accb[RT][8];
    #pragma unroll
    for (int r = 0; r < RT; ++r)
        #pragma unroll
        for (int j = 0; j < 8; ++j) { accg[r][j] = 0.f; accb[r][j] = 0.f; }

    for (int k = 0; k < DIN; k += 4) {
        float4 u4[RT], v4[RT];
        #pragma unroll
        for (int r = 0; r < RT; ++r) {
            u4[r] = *(const float4*)&sU[(r0 + r) * STRIDE + k];
            v4[r] = *(const float4*)&sV[(r0 + r) * STRIDE + k];
        }
        #pragma unroll
        for (int kk = 0; kk < 4; ++kk) {
            float4 wg0 = *(const float4*)&sWgc[(k + kk) * DOUT + c0];
            float4 wg1 = *(const float4*)&sWgc[(k + kk) * DOUT + c0 + 4];
            float4 wb0 = *(const float4*)&sWbi[(k + kk) * DOUT + c0];
            float4 wb1 = *(const float4*)&sWbi[(k + kk) * DOUT + c0 + 4];
            #pragma unroll
            for (int r = 0; r < RT; ++r) {
                float u = ((const float*)&u4[r])[kk];
                float v = ((const float*)&v4[r])[kk];
                accg[r][0] = fmaf(u, wg0.x, accg[r][0]);
                accg[r][1] = fmaf(u, wg0.y, accg[r][1]);
                accg[r][2] = fmaf(u, wg0.z, accg[r][2]);
                accg[r][3] = fmaf(u, wg0.w, accg[r][3]);
                accg[r][4] = fmaf(u, wg1.x, accg[r][4]);
                accg[r][5] = fmaf(u, wg1.y, accg[r][5]);
                accg[r][6] = fmaf(u, wg1.z, accg[r][6]);
                accg[r][7] = fmaf(u, wg1.w, accg[r][7]);
                accb[r][0] = fmaf(v, wb0.x, accb[r][0]);
                accb[r][1] = fmaf(v, wb0.y, accb[r][1]);
                accb[r][2] = fmaf(v, wb0.z, accb[r][2]);
                accb[r][3] = fmaf(v, wb0.w, accb[r][3]);
                accb[r][4] = fmaf(v, wb1.x, accb[r][4]);
                accb[r][5] = fmaf(v, wb1.y, accb[r][5]);
                accb[r][6] = fmaf(v, wb1.z, accb[r][6]);
                accb[r][7] = fmaf(v, wb1.w, accb[r][7]);
            }
        }
    }

    float4 bg0 = *(const float4*)&bgc[c0];
    float4 bg1 = *(const float4*)&bgc[c0 + 4];
    float4 bb0 = *(const float4*)&bbi[c0];
    float4 bb1 = *(const float4*)&bbi[c0 + 4];
    float bg[8] = {bg0.x, bg0.y, bg0.z, bg0.w, bg1.x, bg1.y, bg1.z, bg1.w};
    float bb[8] = {bb0.x, bb0.y, bb0.z, bb0.w, bb1.x, bb1.y, bb1.z, bb1.w};

    #pragma unroll
    for (int r = 0; r < RT; ++r) {
        int n = base + r0 + r;
        if (n < N_NODES) {
            float o[8];
            #pragma unroll
            for (int j = 0; j < 8; ++j) {
                float g = accg[r][j] + bg[j];
                float b2 = accb[r][j] + bb[j];
                g = g > 0.f ? g : SLOPE * g;
                b2 = b2 > 0.f ? b2 : SLOPE * b2;
                o[j] = g + b2;
            }
            float* dst = ego_out + (size_t)n * DOUT + c0;
            *(float4*)dst       = make_float4(o[0], o[1], o[2], o[3]);
            *(float4*)(dst + 4) = make_float4(o[4], o[5], o[6], o[7]);
        }
    }
}

// ---------------------------------------------------------------------------
// Gather: out rows = [ego0(64) | norm(ego1)(64) | norm(ego2)(32) | norm(ego3)(16)]
// ---------------------------------------------------------------------------
__global__ __launch_bounds__(64)
void gather_k(const int* __restrict__ users, const int* __restrict__ pos,
              const int* __restrict__ neg,
              const float* __restrict__ user_emb, const float* __restrict__ ent_emb,
              const float* __restrict__ ego1, const float* __restrict__ ego2,
              const float* __restrict__ ego3,
              float* __restrict__ out) {
    int r = blockIdx.x;
    int lane = threadIdx.x;
    int which = r / BATCH;
    int i = r - which * BATCH;
    int node;
    if (which == 0)      node = users[i];
    else if (which == 1) node = N_USERS + pos[i];
    else                 node = N_USERS + neg[i];

    float* o = out + (size_t)r * 176;

    float x0 = (node < N_USERS) ? user_emb[(size_t)node * 64 + lane]
                                : ent_emb[(size_t)(node - N_USERS) * 64 + lane];
    o[lane] = x0;

    float x1 = ego1[(size_t)node * 64 + lane];
    float ss = x1 * x1;
    #pragma unroll
    for (int off = 32; off > 0; off >>= 1) ss += __shfl_xor(ss, off, 64);
    o[64 + lane] = x1 / fmaxf(sqrtf(ss), EPSF);

    float x2 = (lane < 32) ? ego2[(size_t)node * 32 + lane] : 0.f;
    float ss2 = x2 * x2;
    #pragma unroll
    for (int off = 32; off > 0; off >>= 1) ss2 += __shfl_xor(ss2, off, 64);
    if (lane < 32) o[128 + lane] = x2 / fmaxf(sqrtf(ss2), EPSF);

    float x3 = (lane < 16) ? ego3[(size_t)node * 16 + lane] : 0.f;
    float ss3 = x3 * x3;
    #pragma unroll
    for (int off = 32; off > 0; off >>= 1) ss3 += __shfl_xor(ss3, off, 64);
    if (lane < 16) o[160 + lane] = x3 / fmaxf(sqrtf(ss3), EPSF);
}

// ---------------------------------------------------------------------------
extern "C" void kernel_launch(void* const* d_in, const int* in_sizes, int n_in,
                              void* d_out, int out_size, void* d_ws, size_t ws_size,
                              hipStream_t stream) {
    const int*   users    = (const int*)d_in[0];
    const int*   pos      = (const int*)d_in[1];
    const int*   neg      = (const int*)d_in[2];
    const int*   all_h    = (const int*)d_in[3];
    const int*   all_t    = (const int*)d_in[4];
    const float* A        = (const float*)d_in[5];
    const float* user_emb = (const float*)d_in[6];
    const float* ent_emb  = (const float*)d_in[7];
    const float* Wgc0 = (const float*)d_in[8];
    const float* bgc0 = (const float*)d_in[9];
    const float* Wbi0 = (const float*)d_in[10];
    const float* bbi0 = (const float*)d_in[11];
    const float* Wgc1 = (const float*)d_in[12];
    const float* bgc1 = (const float*)d_in[13];
    const float* Wbi1 = (const float*)d_in[14];
    const float* bbi1 = (const float*)d_in[15];
    const float* Wgc2 = (const float*)d_in[16];
    const float* bgc2 = (const float*)d_in[17];
    const float* Wbi2 = (const float*)d_in[18];
    const float* bbi2 = (const float*)d_in[19];

    // ---- workspace carve-up (256B-aligned). rec is dead after L2's side
    // pass, so ego3 aliases its head to stay within the proven ws budget.
    char* p = (char*)d_ws;
    int*   gcursor = (int*)p;    p += ((size_t)NBUK * 4 + 255) & ~255ull;
    int2*  rec     = (int2*)p;   char* rec_base = p;
    p += ((size_t)NBUK * CAP * 8 + 255) & ~255ull;
    float* side    = (float*)p;  p += ((size_t)N_NODES * 64 * 4 + 255) & ~255ull;
    float* ego1    = (float*)p;  p += ((size_t)N_NODES * 64 * 4 + 255) & ~255ull;
    float* ego2    = (float*)p;  p += ((size_t)N_NODES * 32 * 4 + 255) & ~255ull;
    float* ego3    = (float*)rec_base;   // aliases rec (safe: rec dead by then)
    float* out     = (float*)d_out;

    // ---- bucket partition (once; edges shared across layers) ----
    (void)hipMemsetAsync(gcursor, 0, (size_t)NBUK * 4, stream);
    partition_k<<<NPB, 256, 0, stream>>>(all_h, all_t, A, gcursor, rec);

    // ---- layer 0: 64 -> 64 ----
    bucket_side_k<64, true><<<NBUK, 256, 0, stream>>>(
        gcursor, rec, nullptr, user_emb, ent_emb, side);
    transform_k<64, 64, 64, true><<<(N_NODES + 63) / 64, 256, 0, stream>>>(
        nullptr, user_emb, ent_emb, side, Wgc0, bgc0, Wbi0, bbi0, ego1);

    // ---- layer 1: 64 -> 32 ----
    bucket_side_k<64, false><<<NBUK, 256, 0, stream>>>(
        gcursor, rec, ego1, nullptr, nullptr, side);
    transform_k<64, 32, 64, false><<<(N_NODES + 63) / 64, 256, 0, stream>>>(
        ego1, nullptr, nullptr, side, Wgc1, bgc1, Wbi1, bbi1, ego2);

    // ---- layer 2: 32 -> 16 ----
    bucket_side_k<32, false><<<NBUK, 256, 0, stream>>>(
        gcursor, rec, ego2, nullptr, nullptr, side);
    transform_k<32, 16, 128, false><<<(N_NODES + 127) / 128, 256, 0, stream>>>(
        ego2, nullptr, nullptr, side, Wgc2, bgc2, Wbi2, bbi2, ego3);

    // ---- final gather + lazy normalization ----
    gather_k<<<3 * BATCH, 64, 0, stream>>>(
        users, pos, neg, user_emb, ent_emb, ego1, ego2, ego3, out);
}

// Round 8
// 756.494 us; speedup vs baseline: 4.0243x; 4.0243x over previous
//
#include <hip/hip_runtime.h>
#include <math.h>

#define N_USERS    50000
#define N_ENTITIES 100000
#define N_NODES    150000
#define N_EDGES    3000000
#define BATCH      8192
#define SLOPE      0.2f
#define EPSF       1e-12f

// bucket partition: bucket = h>>6 (64 nodes per bucket)
#define NBUK   2344            // ceil(150000/64)
#define CAP    1536            // per-bucket capacity (mean 1280, sd 36: +7.1 sd)
#define BLK_E  32768           // edges per partition block
#define NPB    ((N_EDGES + BLK_E - 1) / BLK_E)   // 92

// ---------------------------------------------------------------------------
// partition_k: single-pass bucket scatter. Record: {t | (h&63)<<18, bits(a)}.
// Per-(block,bucket) windows are contiguous -> minimal write amplification.
// ---------------------------------------------------------------------------
__global__ __launch_bounds__(256)
void partition_k(const int* __restrict__ all_h, const int* __restrict__ all_t,
                 const float* __restrict__ A,
                 int* __restrict__ gcursor, int2* __restrict__ rec) {
    __shared__ int hist[NBUK];
    __shared__ int base[NBUK];
    __shared__ int cnt2[NBUK];
    int t = threadIdx.x;
    for (int i = t; i < NBUK; i += 256) { hist[i] = 0; cnt2[i] = 0; }
    __syncthreads();

    int e0 = blockIdx.x * BLK_E;
    int e1 = e0 + BLK_E; if (e1 > N_EDGES) e1 = N_EDGES;

    for (int e = e0 + t; e < e1; e += 256)
        atomicAdd(&hist[all_h[e] >> 6], 1);
    __syncthreads();

    for (int i = t; i < NBUK; i += 256)
        base[i] = hist[i] ? atomicAdd(&gcursor[i], hist[i]) : 0;
    __syncthreads();

    for (int e = e0 + t; e < e1; e += 256) {
        int h = all_h[e];
        int b = h >> 6;
        int r = base[b] + atomicAdd(&cnt2[b], 1);
        if (r < CAP)   // 7+ sigma margin; OOB guard only
            rec[(size_t)b * CAP + r] =
                make_int2(all_t[e] | ((h & 63) << 18), __float_as_int(A[e]));
    }
}

// ---------------------------------------------------------------------------
// local_sort_k: one block per bucket. Load records to LDS, 64-bin histogram
// + wave scan, scatter sorted (h-grouped) back IN PLACE (window is private),
// emit per-node (start,end) ranges. Int atomics only, ~1 per record.
// ---------------------------------------------------------------------------
__global__ __launch_bounds__(256)
void local_sort_k(const int* __restrict__ gcursor, int2* __restrict__ rec,
                  int2* __restrict__ range) {
    __shared__ int2 sin[CAP];
    __shared__ int2 sout[CAP];
    __shared__ int cnt64[64];
    __shared__ int pos64[64];
    int b = blockIdx.x, t = threadIdx.x;
    int cnt = gcursor[b]; if (cnt > CAP) cnt = CAP;

    if (t < 64) cnt64[t] = 0;
    __syncthreads();

    for (int i = t; i < cnt; i += 256) {
        int2 p = rec[(size_t)b * CAP + i];
        sin[i] = p;
        atomicAdd(&cnt64[(p.x >> 18) & 63], 1);
    }
    __syncthreads();

    if (t < 64) {   // exclusive scan of 64 counts in wave 0
        int v = cnt64[t];
        int sum = v;
        #pragma unroll
        for (int off = 1; off < 64; off <<= 1) {
            int x = __shfl_up(sum, off, 64);
            if (t >= off) sum += x;
        }
        pos64[t] = sum - v;
    }
    __syncthreads();

    for (int i = t; i < cnt; i += 256) {
        int2 p = sin[i];
        int l = (p.x >> 18) & 63;
        int dst = atomicAdd(&pos64[l], 1);
        sout[dst] = make_int2(p.x & 0x3FFFF, p.y);   // strip h bits
    }
    __syncthreads();

    for (int i = t; i < cnt; i += 256)
        rec[(size_t)b * CAP + i] = sout[i];

    if (t < 64) {   // re-derive starts (pos64 was consumed)
        int v = cnt64[t];
        int sum = v;
        #pragma unroll
        for (int off = 1; off < 64; off <<= 1) {
            int x = __shfl_up(sum, off, 64);
            if (t >= off) sum += x;
        }
        int start = b * CAP + (sum - v);
        int node = b * 64 + t;
        if (node < N_NODES) range[node] = make_int2(start, start + v);
    }
}

// ---------------------------------------------------------------------------
// side_k: wave-per-node CSR segment-sum (R6 structure, range-indexed).
//   side[h] = sum_e A_e * ego[t_e]     8x unrolled, no LDS, no atomics.
// ---------------------------------------------------------------------------
template<int DIN, bool CONCAT>
__global__ __launch_bounds__(256)
void side_k(const int2* __restrict__ range,
            const int2* __restrict__ rec,
            const float* __restrict__ ego_in,
            const float* __restrict__ user_emb, const float* __restrict__ ent_emb,
            float* __restrict__ side) {
    int w = threadIdx.x >> 6;
    int lane = threadIdx.x & 63;
    int h = blockIdx.x * 4 + w;

    int2 rg = range[h];
    int e0 = rg.x, e1 = rg.y;

    if (DIN == 64) {
        float acc = 0.f;
        int e = e0;
        #define ROW64(t) (CONCAT ? (((t) < N_USERS) ? (user_emb + (size_t)(t) * 64) \
                                                    : (ent_emb + (size_t)((t) - N_USERS) * 64)) \
                                 : (ego_in + (size_t)(t) * 64))
        for (; e + 8 <= e1; e += 8) {
            int2 p0 = rec[e + 0];
            int2 p1 = rec[e + 1];
            int2 p2 = rec[e + 2];
            int2 p3 = rec[e + 3];
            int2 p4 = rec[e + 4];
            int2 p5 = rec[e + 5];
            int2 p6 = rec[e + 6];
            int2 p7 = rec[e + 7];
            float x0 = ROW64(p0.x)[lane];
            float x1 = ROW64(p1.x)[lane];
            float x2 = ROW64(p2.x)[lane];
            float x3 = ROW64(p3.x)[lane];
            float x4 = ROW64(p4.x)[lane];
            float x5 = ROW64(p5.x)[lane];
            float x6 = ROW64(p6.x)[lane];
            float x7 = ROW64(p7.x)[lane];
            acc = fmaf(__int_as_float(p0.y), x0, acc);
            acc = fmaf(__int_as_float(p1.y), x1, acc);
            acc = fmaf(__int_as_float(p2.y), x2, acc);
            acc = fmaf(__int_as_float(p3.y), x3, acc);
            acc = fmaf(__int_as_float(p4.y), x4, acc);
            acc = fmaf(__int_as_float(p5.y), x5, acc);
            acc = fmaf(__int_as_float(p6.y), x6, acc);
            acc = fmaf(__int_as_float(p7.y), x7, acc);
        }
        for (; e < e1; ++e) {
            int2 p = rec[e];
            acc = fmaf(__int_as_float(p.y), ROW64(p.x)[lane], acc);
        }
        #undef ROW64
        side[(size_t)h * 64 + lane] = acc;
    } else {  // DIN == 32: two half-waves split the edges, combine via shfl
        int col = lane & 31;
        int half = lane >> 5;
        float acc = 0.f;
        int e = e0 + half;
        for (; e + 6 < e1; e += 8) {
            int2 p0 = rec[e + 0];
            int2 p1 = rec[e + 2];
            int2 p2 = rec[e + 4];
            int2 p3 = rec[e + 6];
            float x0 = ego_in[(size_t)p0.x * 32 + col];
            float x1 = ego_in[(size_t)p1.x * 32 + col];
            float x2 = ego_in[(size_t)p2.x * 32 + col];
            float x3 = ego_in[(size_t)p3.x * 32 + col];
            acc = fmaf(__int_as_float(p0.y), x0, acc);
            acc = fmaf(__int_as_float(p1.y), x1, acc);
            acc = fmaf(__int_as_float(p2.y), x2, acc);
            acc = fmaf(__int_as_float(p3.y), x3, acc);
        }
        for (; e < e1; e += 2) {
            int2 p = rec[e];
            acc = fmaf(__int_as_float(p.y), ego_in[(size_t)p.x * 32 + col], acc);
        }
        acc += __shfl_xor(acc, 32, 64);
        if (lane < 32) side[(size_t)h * 32 + lane] = acc;
    }
}

// ---------------------------------------------------------------------------
// transform_k: tiled vector GEMM over node rows (unchanged).
// ---------------------------------------------------------------------------
template<int DIN, int DOUT, int TILE_ROWS, bool CONCAT>
__global__ __launch_bounds__(256)
void transform_k(const float* __restrict__ ego_in,
                 const float* __restrict__ user_emb, const float* __restrict__ ent_emb,
                 const float* __restrict__ side,
                 const float* __restrict__ Wgc, const float* __restrict__ bgc,
                 const float* __restrict__ Wbi, const float* __restrict__ bbi,
                 float* __restrict__ ego_out) {
    constexpr int NG = DOUT / 8;
    constexpr int RG = 256 / NG;
    constexpr int RT = TILE_ROWS / RG;
    constexpr int STRIDE = DIN + 4;
    constexpr int KC = DIN / 4;

    __shared__ float sWgc[DIN * DOUT], sWbi[DIN * DOUT];
    __shared__ float sU[TILE_ROWS * STRIDE], sV[TILE_ROWS * STRIDE];

    int t = threadIdx.x;

    for (int i = t * 4; i < DIN * DOUT; i += 1024) {
        *(float4*)&sWgc[i] = *(const float4*)&Wgc[i];
        *(float4*)&sWbi[i] = *(const float4*)&Wbi[i];
    }

    int base = blockIdx.x * TILE_ROWS;
    for (int f = t; f < TILE_ROWS * KC; f += 256) {
        int row = f / KC, kc = f % KC;
        int n = base + row;
        int nc = n < N_NODES ? n : N_NODES - 1;
        const float* erow;
        if (CONCAT) {
            erow = (nc < N_USERS) ? user_emb + (size_t)nc * 64
                                  : ent_emb + (size_t)(nc - N_USERS) * 64;
        } else {
            erow = ego_in + (size_t)nc * DIN;
        }
        float4 e4 = ((const float4*)erow)[kc];
        float4 s4 = ((const float4*)(side + (size_t)nc * DIN))[kc];
        float4 u4, v4;
        u4.x = e4.x + s4.x; u4.y = e4.y + s4.y; u4.z = e4.z + s4.z; u4.w = e4.w + s4.w;
        v4.x = e4.x * s4.x; v4.y = e4.y * s4.y; v4.z = e4.z * s4.z; v4.w = e4.w * s4.w;
        *(float4*)&sU[row * STRIDE + kc * 4] = u4;
        *(float4*)&sV[row * STRIDE + kc * 4] = v4;
    }
    __syncthreads();

    int cg = t % NG, rg = t / NG;
    int c0 = cg * 8;
    int r0 = rg * RT;

    float accg[RT][8], accb[RT][8];
    #pragma unroll
    for (int r = 0; r < RT; ++r)
        #pragma unroll
        for (int j = 0; j < 8; ++j) { accg[r][j] = 0.f; accb[r][j] = 0.f; }

    for (int k = 0; k < DIN; k += 4) {
        float4 u4[RT], v4[RT];
        #pragma unroll
        for (int r = 0; r < RT; ++r) {
            u4[r] = *(const float4*)&sU[(r0 + r) * STRIDE + k];
            v4[r] = *(const float4*)&sV[(r0 + r) * STRIDE + k];
        }
        #pragma unroll
        for (int kk = 0; kk < 4; ++kk) {
            float4 wg0 = *(const float4*)&sWgc[(k + kk) * DOUT + c0];
            float4 wg1 = *(const float4*)&sWgc[(k + kk) * DOUT + c0 + 4];
            float4 wb0 = *(const float4*)&sWbi[(k + kk) * DOUT + c0];
            float4 wb1 = *(const float4*)&sWbi[(k + kk) * DOUT + c0 + 4];
            #pragma unroll
            for (int r = 0; r < RT; ++r) {
                float u = ((const float*)&u4[r])[kk];
                float v = ((const float*)&v4[r])[kk];
                accg[r][0] = fmaf(u, wg0.x, accg[r][0]);
                accg[r][1] = fmaf(u, wg0.y, accg[r][1]);
                accg[r][2] = fmaf(u, wg0.z, accg[r][2]);
                accg[r][3] = fmaf(u, wg0.w, accg[r][3]);
                accg[r][4] = fmaf(u, wg1.x, accg[r][4]);
                accg[r][5] = fmaf(u, wg1.y, accg[r][5]);
                accg[r][6] = fmaf(u, wg1.z, accg[r][6]);
                accg[r][7] = fmaf(u, wg1.w, accg[r][7]);
                accb[r][0] = fmaf(v, wb0.x, accb[r][0]);
                accb[r][1] = fmaf(v, wb0.y, accb[r][1]);
                accb[r][2] = fmaf(v, wb0.z, accb[r][2]);
                accb[r][3] = fmaf(v, wb0.w, accb[r][3]);
                accb[r][4] = fmaf(v, wb1.x, accb[r][4]);
                accb[r][5] = fmaf(v, wb1.y, accb[r][5]);
                accb[r][6] = fmaf(v, wb1.z, accb[r][6]);
                accb[r][7] = fmaf(v, wb1.w, accb[r][7]);
            }
        }
    }

    float4 bg0 = *(const float4*)&bgc[c0];
    float4 bg1 = *(const float4*)&bgc[c0 + 4];
    float4 bb0 = *(const float4*)&bbi[c0];
    float4 bb1 = *(const float4*)&bbi[c0 + 4];
    float bg[8] = {bg0.x, bg0.y, bg0.z, bg0.w, bg1.x, bg1.y, bg1.z, bg1.w};
    float bb[8] = {bb0.x, bb0.y, bb0.z, bb0.w, bb1.x, bb1.y, bb1.z, bb1.w};

    #pragma unroll
    for (int r = 0; r < RT; ++r) {
        int n = base + r0 + r;
        if (n < N_NODES) {
            float o[8];
            #pragma unroll
            for (int j = 0; j < 8; ++j) {
                float g = accg[r][j] + bg[j];
                float b2 = accb[r][j] + bb[j];
                g = g > 0.f ? g : SLOPE * g;
                b2 = b2 > 0.f ? b2 : SLOPE * b2;
                o[j] = g + b2;
            }
            float* dst = ego_out + (size_t)n * DOUT + c0;
            *(float4*)dst       = make_float4(o[0], o[1], o[2], o[3]);
            *(float4*)(dst + 4) = make_float4(o[4], o[5], o[6], o[7]);
        }
    }
}

// ---------------------------------------------------------------------------
// Gather: out rows = [ego0(64) | norm(ego1)(64) | norm(ego2)(32) | norm(ego3)(16)]
// ---------------------------------------------------------------------------
__global__ __launch_bounds__(64)
void gather_k(const int* __restrict__ users, const int* __restrict__ pos,
              const int* __restrict__ neg,
              const float* __restrict__ user_emb, const float* __restrict__ ent_emb,
              const float* __restrict__ ego1, const float* __restrict__ ego2,
              const float* __restrict__ ego3,
              float* __restrict__ out) {
    int r = blockIdx.x;
    int lane = threadIdx.x;
    int which = r / BATCH;
    int i = r - which * BATCH;
    int node;
    if (which == 0)      node = users[i];
    else if (which == 1) node = N_USERS + pos[i];
    else                 node = N_USERS + neg[i];

    float* o = out + (size_t)r * 176;

    float x0 = (node < N_USERS) ? user_emb[(size_t)node * 64 + lane]
                                : ent_emb[(size_t)(node - N_USERS) * 64 + lane];
    o[lane] = x0;

    float x1 = ego1[(size_t)node * 64 + lane];
    float ss = x1 * x1;
    #pragma unroll
    for (int off = 32; off > 0; off >>= 1) ss += __shfl_xor(ss, off, 64);
    o[64 + lane] = x1 / fmaxf(sqrtf(ss), EPSF);

    float x2 = (lane < 32) ? ego2[(size_t)node * 32 + lane] : 0.f;
    float ss2 = x2 * x2;
    #pragma unroll
    for (int off = 32; off > 0; off >>= 1) ss2 += __shfl_xor(ss2, off, 64);
    if (lane < 32) o[128 + lane] = x2 / fmaxf(sqrtf(ss2), EPSF);

    float x3 = (lane < 16) ? ego3[(size_t)node * 16 + lane] : 0.f;
    float ss3 = x3 * x3;
    #pragma unroll
    for (int off = 32; off > 0; off >>= 1) ss3 += __shfl_xor(ss3, off, 64);
    if (lane < 16) o[160 + lane] = x3 / fmaxf(sqrtf(ss3), EPSF);
}

// ---------------------------------------------------------------------------
extern "C" void kernel_launch(void* const* d_in, const int* in_sizes, int n_in,
                              void* d_out, int out_size, void* d_ws, size_t ws_size,
                              hipStream_t stream) {
    const int*   users    = (const int*)d_in[0];
    const int*   pos      = (const int*)d_in[1];
    const int*   neg      = (const int*)d_in[2];
    const int*   all_h    = (const int*)d_in[3];
    const int*   all_t    = (const int*)d_in[4];
    const float* A        = (const float*)d_in[5];
    const float* user_emb = (const float*)d_in[6];
    const float* ent_emb  = (const float*)d_in[7];
    const float* Wgc0 = (const float*)d_in[8];
    const float* bgc0 = (const float*)d_in[9];
    const float* Wbi0 = (const float*)d_in[10];
    const float* bbi0 = (const float*)d_in[11];
    const float* Wgc1 = (const float*)d_in[12];
    const float* bgc1 = (const float*)d_in[13];
    const float* Wbi1 = (const float*)d_in[14];
    const float* bbi1 = (const float*)d_in[15];
    const float* Wgc2 = (const float*)d_in[16];
    const float* bgc2 = (const float*)d_in[17];
    const float* Wbi2 = (const float*)d_in[18];
    const float* bbi2 = (const float*)d_in[19];

    // ---- workspace carve-up (256B-aligned). rec is dead after L2's side
    // pass, so ego3 aliases its head.
    char* p = (char*)d_ws;
    int*   gcursor = (int*)p;    p += ((size_t)NBUK * 4 + 255) & ~255ull;
    int2*  rec     = (int2*)p;   char* rec_base = p;
    p += ((size_t)NBUK * CAP * 8 + 255) & ~255ull;
    int2*  range   = (int2*)p;   p += ((size_t)N_NODES * 8 + 255) & ~255ull;
    float* side    = (float*)p;  p += ((size_t)N_NODES * 64 * 4 + 255) & ~255ull;
    float* ego1    = (float*)p;  p += ((size_t)N_NODES * 64 * 4 + 255) & ~255ull;
    float* ego2    = (float*)p;  p += ((size_t)N_NODES * 32 * 4 + 255) & ~255ull;
    float* ego3    = (float*)rec_base;   // aliases rec (dead by then)
    float* out     = (float*)d_out;

    const int nodeBlocks = N_NODES / 4;   // 150000 % 4 == 0

    // ---- bucket partition + per-bucket local sort (once) ----
    (void)hipMemsetAsync(gcursor, 0, (size_t)NBUK * 4, stream);
    partition_k<<<NPB, 256, 0, stream>>>(all_h, all_t, A, gcursor, rec);
    local_sort_k<<<NBUK, 256, 0, stream>>>(gcursor, rec, range);

    // ---- layer 0: 64 -> 64 ----
    side_k<64, true><<<nodeBlocks, 256, 0, stream>>>(
        range, rec, nullptr, user_emb, ent_emb, side);
    transform_k<64, 64, 64, true><<<(N_NODES + 63) / 64, 256, 0, stream>>>(
        nullptr, user_emb, ent_emb, side, Wgc0, bgc0, Wbi0, bbi0, ego1);

    // ---- layer 1: 64 -> 32 ----
    side_k<64, false><<<nodeBlocks, 256, 0, stream>>>(
        range, rec, ego1, nullptr, nullptr, side);
    transform_k<64, 32, 64, false><<<(N_NODES + 63) / 64, 256, 0, stream>>>(
        ego1, nullptr, nullptr, side, Wgc1, bgc1, Wbi1, bbi1, ego2);

    // ---- layer 2: 32 -> 16 ----
    side_k<32, false><<<nodeBlocks, 256, 0, stream>>>(
        range, rec, ego2, nullptr, nullptr, side);
    transform_k<32, 16, 128, false><<<(N_NODES + 127) / 128, 256, 0, stream>>>(
        ego2, nullptr, nullptr, side, Wgc2, bgc2, Wbi2, bbi2, ego3);

    // ---- final gather + lazy normalization ----
    gather_k<<<3 * BATCH, 64, 0, stream>>>(
        users, pos, neg, user_emb, ent_emb, ego1, ego2, ego3, out);
}

// Round 9
// 677.464 us; speedup vs baseline: 4.4938x; 1.1167x over previous
//
#include <hip/hip_runtime.h>
#include <math.h>

#define N_USERS    50000
#define N_ENTITIES 100000
#define N_NODES    150000
#define N_EDGES    3000000
#define BATCH      8192
#define SLOPE      0.2f
#define EPSF       1e-12f

// bucket partition: bucket = h>>6 (64 nodes per bucket)
#define NBUK   2344            // ceil(150000/64)
#define CAP    1536            // per-bucket capacity (mean 1280, sd 36: +7.1 sd)
#define BLK_E  8192            // edges per partition block (occupancy >> window size)
#define NPB    ((N_EDGES + BLK_E - 1) / BLK_E)   // 367

// ---------------------------------------------------------------------------
// partition_k: single-pass bucket scatter. Record: {t | (h&63)<<18, bits(a)}.
// Per-(block,bucket) windows are contiguous. hist doubles as claimed base
// after the claim pass (2 LDS arrays, 18.8 KB -> no LDS occupancy cap).
// ---------------------------------------------------------------------------
__global__ __launch_bounds__(256)
void partition_k(const int* __restrict__ all_h, const int* __restrict__ all_t,
                 const float* __restrict__ A,
                 int* __restrict__ gcursor, int2* __restrict__ rec) {
    __shared__ int hist[NBUK];   // counts, then claimed global base
    __shared__ int cnt2[NBUK];   // local running offset
    int t = threadIdx.x;
    for (int i = t; i < NBUK; i += 256) { hist[i] = 0; cnt2[i] = 0; }
    __syncthreads();

    int e0 = blockIdx.x * BLK_E;
    int e1 = e0 + BLK_E; if (e1 > N_EDGES) e1 = N_EDGES;

    for (int e = e0 + t; e < e1; e += 256)
        atomicAdd(&hist[all_h[e] >> 6], 1);
    __syncthreads();

    for (int i = t; i < NBUK; i += 256) {
        int c = hist[i];
        hist[i] = c ? atomicAdd(&gcursor[i], c) : 0;   // hist becomes base
    }
    __syncthreads();

    for (int e = e0 + t; e < e1; e += 256) {
        int h = all_h[e];
        int b = h >> 6;
        int r = hist[b] + atomicAdd(&cnt2[b], 1);
        if (r < CAP)   // 7+ sigma margin; OOB guard only
            rec[(size_t)b * CAP + r] =
                make_int2(all_t[e] | ((h & 63) << 18), __float_as_int(A[e]));
    }
}

// ---------------------------------------------------------------------------
// local_sort_k: one block per bucket. Load records to LDS, 64-bin histogram
// + wave scan, scatter sorted (h-grouped) back IN PLACE (window is private),
// emit per-node (start,end) ranges. Int atomics only, ~1 per record.
// ---------------------------------------------------------------------------
__global__ __launch_bounds__(256)
void local_sort_k(const int* __restrict__ gcursor, int2* __restrict__ rec,
                  int2* __restrict__ range) {
    __shared__ int2 sin[CAP];
    __shared__ int2 sout[CAP];
    __shared__ int cnt64[64];
    __shared__ int pos64[64];
    int b = blockIdx.x, t = threadIdx.x;
    int cnt = gcursor[b]; if (cnt > CAP) cnt = CAP;

    if (t < 64) cnt64[t] = 0;
    __syncthreads();

    for (int i = t; i < cnt; i += 256) {
        int2 p = rec[(size_t)b * CAP + i];
        sin[i] = p;
        atomicAdd(&cnt64[(p.x >> 18) & 63], 1);
    }
    __syncthreads();

    if (t < 64) {   // exclusive scan of 64 counts in wave 0
        int v = cnt64[t];
        int sum = v;
        #pragma unroll
        for (int off = 1; off < 64; off <<= 1) {
            int x = __shfl_up(sum, off, 64);
            if (t >= off) sum += x;
        }
        pos64[t] = sum - v;
    }
    __syncthreads();

    for (int i = t; i < cnt; i += 256) {
        int2 p = sin[i];
        int l = (p.x >> 18) & 63;
        int dst = atomicAdd(&pos64[l], 1);
        sout[dst] = make_int2(p.x & 0x3FFFF, p.y);   // strip h bits
    }
    __syncthreads();

    for (int i = t; i < cnt; i += 256)
        rec[(size_t)b * CAP + i] = sout[i];

    if (t < 64) {   // re-derive starts (pos64 was consumed)
        int v = cnt64[t];
        int sum = v;
        #pragma unroll
        for (int off = 1; off < 64; off <<= 1) {
            int x = __shfl_up(sum, off, 64);
            if (t >= off) sum += x;
        }
        int start = b * CAP + (sum - v);
        int node = b * 64 + t;
        if (node < N_NODES) range[node] = make_int2(start, start + v);
    }
}

// ---------------------------------------------------------------------------
// side_k: wave-per-node CSR segment-sum (range-indexed).
//   side[h] = sum_e A_e * ego[t_e]     8x unrolled, no LDS, no atomics.
// ---------------------------------------------------------------------------
template<int DIN, bool CONCAT>
__global__ __launch_bounds__(256)
void side_k(const int2* __restrict__ range,
            const int2* __restrict__ rec,
            const float* __restrict__ ego_in,
            const float* __restrict__ user_emb, const float* __restrict__ ent_emb,
            float* __restrict__ side) {
    int w = threadIdx.x >> 6;
    int lane = threadIdx.x & 63;
    int h = blockIdx.x * 4 + w;

    int2 rg = range[h];
    int e0 = rg.x, e1 = rg.y;

    if (DIN == 64) {
        float acc = 0.f;
        int e = e0;
        #define ROW64(t) (CONCAT ? (((t) < N_USERS) ? (user_emb + (size_t)(t) * 64) \
                                                    : (ent_emb + (size_t)((t) - N_USERS) * 64)) \
                                 : (ego_in + (size_t)(t) * 64))
        for (; e + 8 <= e1; e += 8) {
            int2 p0 = rec[e + 0];
            int2 p1 = rec[e + 1];
            int2 p2 = rec[e + 2];
            int2 p3 = rec[e + 3];
            int2 p4 = rec[e + 4];
            int2 p5 = rec[e + 5];
            int2 p6 = rec[e + 6];
            int2 p7 = rec[e + 7];
            float x0 = ROW64(p0.x)[lane];
            float x1 = ROW64(p1.x)[lane];
            float x2 = ROW64(p2.x)[lane];
            float x3 = ROW64(p3.x)[lane];
            float x4 = ROW64(p4.x)[lane];
            float x5 = ROW64(p5.x)[lane];
            float x6 = ROW64(p6.x)[lane];
            float x7 = ROW64(p7.x)[lane];
            acc = fmaf(__int_as_float(p0.y), x0, acc);
            acc = fmaf(__int_as_float(p1.y), x1, acc);
            acc = fmaf(__int_as_float(p2.y), x2, acc);
            acc = fmaf(__int_as_float(p3.y), x3, acc);
            acc = fmaf(__int_as_float(p4.y), x4, acc);
            acc = fmaf(__int_as_float(p5.y), x5, acc);
            acc = fmaf(__int_as_float(p6.y), x6, acc);
            acc = fmaf(__int_as_float(p7.y), x7, acc);
        }
        for (; e < e1; ++e) {
            int2 p = rec[e];
            acc = fmaf(__int_as_float(p.y), ROW64(p.x)[lane], acc);
        }
        #undef ROW64
        side[(size_t)h * 64 + lane] = acc;
    } else {  // DIN == 32: two half-waves split the edges, combine via shfl
        int col = lane & 31;
        int half = lane >> 5;
        float acc = 0.f;
        int e = e0 + half;
        for (; e + 6 < e1; e += 8) {
            int2 p0 = rec[e + 0];
            int2 p1 = rec[e + 2];
            int2 p2 = rec[e + 4];
            int2 p3 = rec[e + 6];
            float x0 = ego_in[(size_t)p0.x * 32 + col];
            float x1 = ego_in[(size_t)p1.x * 32 + col];
            float x2 = ego_in[(size_t)p2.x * 32 + col];
            float x3 = ego_in[(size_t)p3.x * 32 + col];
            acc = fmaf(__int_as_float(p0.y), x0, acc);
            acc = fmaf(__int_as_float(p1.y), x1, acc);
            acc = fmaf(__int_as_float(p2.y), x2, acc);
            acc = fmaf(__int_as_float(p3.y), x3, acc);
        }
        for (; e < e1; e += 2) {
            int2 p = rec[e];
            acc = fmaf(__int_as_float(p.y), ego_in[(size_t)p.x * 32 + col], acc);
        }
        acc += __shfl_xor(acc, 32, 64);
        if (lane < 32) side[(size_t)h * 32 + lane] = acc;
    }
}

// ---------------------------------------------------------------------------
// transform_k: tiled vector GEMM over node rows (unchanged).
// ---------------------------------------------------------------------------
template<int DIN, int DOUT, int TILE_ROWS, bool CONCAT>
__global__ __launch_bounds__(256)
void transform_k(const float* __restrict__ ego_in,
                 const float* __restrict__ user_emb, const float* __restrict__ ent_emb,
                 const float* __restrict__ side,
                 const float* __restrict__ Wgc, const float* __restrict__ bgc,
                 const float* __restrict__ Wbi, const float* __restrict__ bbi,
                 float* __restrict__ ego_out) {
    constexpr int NG = DOUT / 8;
    constexpr int RG = 256 / NG;
    constexpr int RT = TILE_ROWS / RG;
    constexpr int STRIDE = DIN + 4;
    constexpr int KC = DIN / 4;

    __shared__ float sWgc[DIN * DOUT], sWbi[DIN * DOUT];
    __shared__ float sU[TILE_ROWS * STRIDE], sV[TILE_ROWS * STRIDE];

    int t = threadIdx.x;

    for (int i = t * 4; i < DIN * DOUT; i += 1024) {
        *(float4*)&sWgc[i] = *(const float4*)&Wgc[i];
        *(float4*)&sWbi[i] = *(const float4*)&Wbi[i];
    }

    int base = blockIdx.x * TILE_ROWS;
    for (int f = t; f < TILE_ROWS * KC; f += 256) {
        int row = f / KC, kc = f % KC;
        int n = base + row;
        int nc = n < N_NODES ? n : N_NODES - 1;
        const float* erow;
        if (CONCAT) {
            erow = (nc < N_USERS) ? user_emb + (size_t)nc * 64
                                  : ent_emb + (size_t)(nc - N_USERS) * 64;
        } else {
            erow = ego_in + (size_t)nc * DIN;
        }
        float4 e4 = ((const float4*)erow)[kc];
        float4 s4 = ((const float4*)(side + (size_t)nc * DIN))[kc];
        float4 u4, v4;
        u4.x = e4.x + s4.x; u4.y = e4.y + s4.y; u4.z = e4.z + s4.z; u4.w = e4.w + s4.w;
        v4.x = e4.x * s4.x; v4.y = e4.y * s4.y; v4.z = e4.z * s4.z; v4.w = e4.w * s4.w;
        *(float4*)&sU[row * STRIDE + kc * 4] = u4;
        *(float4*)&sV[row * STRIDE + kc * 4] = v4;
    }
    __syncthreads();

    int cg = t % NG, rg = t / NG;
    int c0 = cg * 8;
    int r0 = rg * RT;

    float accg[RT][8], accb[RT][8];
    #pragma unroll
    for (int r = 0; r < RT; ++r)
        #pragma unroll
        for (int j = 0; j < 8; ++j) { accg[r][j] = 0.f; accb[r][j] = 0.f; }

    for (int k = 0; k < DIN; k += 4) {
        float4 u4[RT], v4[RT];
        #pragma unroll
        for (int r = 0; r < RT; ++r) {
            u4[r] = *(const float4*)&sU[(r0 + r) * STRIDE + k];
            v4[r] = *(const float4*)&sV[(r0 + r) * STRIDE + k];
        }
        #pragma unroll
        for (int kk = 0; kk < 4; ++kk) {
            float4 wg0 = *(const float4*)&sWgc[(k + kk) * DOUT + c0];
            float4 wg1 = *(const float4*)&sWgc[(k + kk) * DOUT + c0 + 4];
            float4 wb0 = *(const float4*)&sWbi[(k + kk) * DOUT + c0];
            float4 wb1 = *(const float4*)&sWbi[(k + kk) * DOUT + c0 + 4];
            #pragma unroll
            for (int r = 0; r < RT; ++r) {
                float u = ((const float*)&u4[r])[kk];
                float v = ((const float*)&v4[r])[kk];
                accg[r][0] = fmaf(u, wg0.x, accg[r][0]);
                accg[r][1] = fmaf(u, wg0.y, accg[r][1]);
                accg[r][2] = fmaf(u, wg0.z, accg[r][2]);
                accg[r][3] = fmaf(u, wg0.w, accg[r][3]);
                accg[r][4] = fmaf(u, wg1.x, accg[r][4]);
                accg[r][5] = fmaf(u, wg1.y, accg[r][5]);
                accg[r][6] = fmaf(u, wg1.z, accg[r][6]);
                accg[r][7] = fmaf(u, wg1.w, accg[r][7]);
                accb[r][0] = fmaf(v, wb0.x, accb[r][0]);
                accb[r][1] = fmaf(v, wb0.y, accb[r][1]);
                accb[r][2] = fmaf(v, wb0.z, accb[r][2]);
                accb[r][3] = fmaf(v, wb0.w, accb[r][3]);
                accb[r][4] = fmaf(v, wb1.x, accb[r][4]);
                accb[r][5] = fmaf(v, wb1.y, accb[r][5]);
                accb[r][6] = fmaf(v, wb1.z, accb[r][6]);
                accb[r][7] = fmaf(v, wb1.w, accb[r][7]);
            }
        }
    }

    float4 bg0 = *(const float4*)&bgc[c0];
    float4 bg1 = *(const float4*)&bgc[c0 + 4];
    float4 bb0 = *(const float4*)&bbi[c0];
    float4 bb1 = *(const float4*)&bbi[c0 + 4];
    float bg[8] = {bg0.x, bg0.y, bg0.z, bg0.w, bg1.x, bg1.y, bg1.z, bg1.w};
    float bb[8] = {bb0.x, bb0.y, bb0.z, bb0.w, bb1.x, bb1.y, bb1.z, bb1.w};

    #pragma unroll
    for (int r = 0; r < RT; ++r) {
        int n = base + r0 + r;
        if (n < N_NODES) {
            float o[8];
            #pragma unroll
            for (int j = 0; j < 8; ++j) {
                float g = accg[r][j] + bg[j];
                float b2 = accb[r][j] + bb[j];
                g = g > 0.f ? g : SLOPE * g;
                b2 = b2 > 0.f ? b2 : SLOPE * b2;
                o[j] = g + b2;
            }
            float* dst = ego_out + (size_t)n * DOUT + c0;
            *(float4*)dst       = make_float4(o[0], o[1], o[2], o[3]);
            *(float4*)(dst + 4) = make_float4(o[4], o[5], o[6], o[7]);
        }
    }
}

// ---------------------------------------------------------------------------
// Gather: out rows = [ego0(64) | norm(ego1)(64) | norm(ego2)(32) | norm(ego3)(16)]
// ---------------------------------------------------------------------------
__global__ __launch_bounds__(64)
void gather_k(const int* __restrict__ users, const int* __restrict__ pos,
              const int* __restrict__ neg,
              const float* __restrict__ user_emb, const float* __restrict__ ent_emb,
              const float* __restrict__ ego1, const float* __restrict__ ego2,
              const float* __restrict__ ego3,
              float* __restrict__ out) {
    int r = blockIdx.x;
    int lane = threadIdx.x;
    int which = r / BATCH;
    int i = r - which * BATCH;
    int node;
    if (which == 0)      node = users[i];
    else if (which == 1) node = N_USERS + pos[i];
    else                 node = N_USERS + neg[i];

    float* o = out + (size_t)r * 176;

    float x0 = (node < N_USERS) ? user_emb[(size_t)node * 64 + lane]
                                : ent_emb[(size_t)(node - N_USERS) * 64 + lane];
    o[lane] = x0;

    float x1 = ego1[(size_t)node * 64 + lane];
    float ss = x1 * x1;
    #pragma unroll
    for (int off = 32; off > 0; off >>= 1) ss += __shfl_xor(ss, off, 64);
    o[64 + lane] = x1 / fmaxf(sqrtf(ss), EPSF);

    float x2 = (lane < 32) ? ego2[(size_t)node * 32 + lane] : 0.f;
    float ss2 = x2 * x2;
    #pragma unroll
    for (int off = 32; off > 0; off >>= 1) ss2 += __shfl_xor(ss2, off, 64);
    if (lane < 32) o[128 + lane] = x2 / fmaxf(sqrtf(ss2), EPSF);

    float x3 = (lane < 16) ? ego3[(size_t)node * 16 + lane] : 0.f;
    float ss3 = x3 * x3;
    #pragma unroll
    for (int off = 32; off > 0; off >>= 1) ss3 += __shfl_xor(ss3, off, 64);
    if (lane < 16) o[160 + lane] = x3 / fmaxf(sqrtf(ss3), EPSF);
}

// ---------------------------------------------------------------------------
extern "C" void kernel_launch(void* const* d_in, const int* in_sizes, int n_in,
                              void* d_out, int out_size, void* d_ws, size_t ws_size,
                              hipStream_t stream) {
    const int*   users    = (const int*)d_in[0];
    const int*   pos      = (const int*)d_in[1];
    const int*   neg      = (const int*)d_in[2];
    const int*   all_h    = (const int*)d_in[3];
    const int*   all_t    = (const int*)d_in[4];
    const float* A        = (const float*)d_in[5];
    const float* user_emb = (const float*)d_in[6];
    const float* ent_emb  = (const float*)d_in[7];
    const float* Wgc0 = (const float*)d_in[8];
    const float* bgc0 = (const float*)d_in[9];
    const float* Wbi0 = (const float*)d_in[10];
    const float* bbi0 = (const float*)d_in[11];
    const float* Wgc1 = (const float*)d_in[12];
    const float* bgc1 = (const float*)d_in[13];
    const float* Wbi1 = (const float*)d_in[14];
    const float* bbi1 = (const float*)d_in[15];
    const float* Wgc2 = (const float*)d_in[16];
    const float* bgc2 = (const float*)d_in[17];
    const float* Wbi2 = (const float*)d_in[18];
    const float* bbi2 = (const float*)d_in[19];

    // ---- workspace carve-up (256B-aligned). rec is dead after L2's side
    // pass, so ego3 aliases its head.
    char* p = (char*)d_ws;
    int*   gcursor = (int*)p;    p += ((size_t)NBUK * 4 + 255) & ~255ull;
    int2*  rec     = (int2*)p;   char* rec_base = p;
    p += ((size_t)NBUK * CAP * 8 + 255) & ~255ull;
    int2*  range   = (int2*)p;   p += ((size_t)N_NODES * 8 + 255) & ~255ull;
    float* side    = (float*)p;  p += ((size_t)N_NODES * 64 * 4 + 255) & ~255ull;
    float* ego1    = (float*)p;  p += ((size_t)N_NODES * 64 * 4 + 255) & ~255ull;
    float* ego2    = (float*)p;  p += ((size_t)N_NODES * 32 * 4 + 255) & ~255ull;
    float* ego3    = (float*)rec_base;   // aliases rec (dead by then)
    float* out     = (float*)d_out;

    const int nodeBlocks = N_NODES / 4;   // 150000 % 4 == 0

    // ---- bucket partition + per-bucket local sort (once) ----
    (void)hipMemsetAsync(gcursor, 0, (size_t)NBUK * 4, stream);
    partition_k<<<NPB, 256, 0, stream>>>(all_h, all_t, A, gcursor, rec);
    local_sort_k<<<NBUK, 256, 0, stream>>>(gcursor, rec, range);

    // ---- layer 0: 64 -> 64 ----
    side_k<64, true><<<nodeBlocks, 256, 0, stream>>>(
        range, rec, nullptr, user_emb, ent_emb, side);
    transform_k<64, 64, 64, true><<<(N_NODES + 63) / 64, 256, 0, stream>>>(
        nullptr, user_emb, ent_emb, side, Wgc0, bgc0, Wbi0, bbi0, ego1);

    // ---- layer 1: 64 -> 32 ----
    side_k<64, false><<<nodeBlocks, 256, 0, stream>>>(
        range, rec, ego1, nullptr, nullptr, side);
    transform_k<64, 32, 64, false><<<(N_NODES + 63) / 64, 256, 0, stream>>>(
        ego1, nullptr, nullptr, side, Wgc1, bgc1, Wbi1, bbi1, ego2);

    // ---- layer 2: 32 -> 16 ----
    side_k<32, false><<<nodeBlocks, 256, 0, stream>>>(
        range, rec, ego2, nullptr, nullptr, side);
    transform_k<32, 16, 128, false><<<(N_NODES + 127) / 128, 256, 0, stream>>>(
        ego2, nullptr, nullptr, side, Wgc2, bgc2, Wbi2, bbi2, ego3);

    // ---- final gather + lazy normalization ----
    gather_k<<<3 * BATCH, 64, 0, stream>>>(
        users, pos, neg, user_emb, ent_emb, ego1, ego2, ego3, out);
}

// Round 10
// 611.564 us; speedup vs baseline: 4.9780x; 1.1078x over previous
//
#include <hip/hip_runtime.h>
#include <math.h>

#define N_USERS    50000
#define N_ENTITIES 100000
#define N_NODES    150000
#define N_EDGES    3000000
#define BATCH      8192
#define SLOPE      0.2f
#define EPSF       1e-12f

// bucket partition: bucket = h>>6 (64 nodes per bucket)
#define NBUK   2344            // ceil(150000/64)
#define CAP    1536            // per-bucket capacity (mean 1280, sd 36: +7.1 sd)
#define BLK_E  8192            // edges per partition block
#define NPB    ((N_EDGES + BLK_E - 1) / BLK_E)   // 367

// ---------------------------------------------------------------------------
// partition_k: single-pass bucket scatter. Record: {t | (h&63)<<18, bits(a)}.
// ---------------------------------------------------------------------------
__global__ __launch_bounds__(256)
void partition_k(const int* __restrict__ all_h, const int* __restrict__ all_t,
                 const float* __restrict__ A,
                 int* __restrict__ gcursor, int2* __restrict__ rec) {
    __shared__ int hist[NBUK];   // counts, then claimed global base
    __shared__ int cnt2[NBUK];   // local running offset
    int t = threadIdx.x;
    for (int i = t; i < NBUK; i += 256) { hist[i] = 0; cnt2[i] = 0; }
    __syncthreads();

    int e0 = blockIdx.x * BLK_E;
    int e1 = e0 + BLK_E; if (e1 > N_EDGES) e1 = N_EDGES;

    for (int e = e0 + t; e < e1; e += 256)
        atomicAdd(&hist[all_h[e] >> 6], 1);
    __syncthreads();

    for (int i = t; i < NBUK; i += 256) {
        int c = hist[i];
        hist[i] = c ? atomicAdd(&gcursor[i], c) : 0;   // hist becomes base
    }
    __syncthreads();

    for (int e = e0 + t; e < e1; e += 256) {
        int h = all_h[e];
        int b = h >> 6;
        int r = hist[b] + atomicAdd(&cnt2[b], 1);
        if (r < CAP)
            rec[(size_t)b * CAP + r] =
                make_int2(all_t[e] | ((h & 63) << 18), __float_as_int(A[e]));
    }
}

// ---------------------------------------------------------------------------
// local_sort_k: per-bucket 64-bin counting sort in LDS -> h-grouped records
// + per-node (start,end) ranges.
// ---------------------------------------------------------------------------
__global__ __launch_bounds__(256)
void local_sort_k(const int* __restrict__ gcursor, int2* __restrict__ rec,
                  int2* __restrict__ range) {
    __shared__ int2 sin[CAP];
    __shared__ int2 sout[CAP];
    __shared__ int cnt64[64];
    __shared__ int pos64[64];
    int b = blockIdx.x, t = threadIdx.x;
    int cnt = gcursor[b]; if (cnt > CAP) cnt = CAP;

    if (t < 64) cnt64[t] = 0;
    __syncthreads();

    for (int i = t; i < cnt; i += 256) {
        int2 p = rec[(size_t)b * CAP + i];
        sin[i] = p;
        atomicAdd(&cnt64[(p.x >> 18) & 63], 1);
    }
    __syncthreads();

    if (t < 64) {
        int v = cnt64[t];
        int sum = v;
        #pragma unroll
        for (int off = 1; off < 64; off <<= 1) {
            int x = __shfl_up(sum, off, 64);
            if (t >= off) sum += x;
        }
        pos64[t] = sum - v;
    }
    __syncthreads();

    for (int i = t; i < cnt; i += 256) {
        int2 p = sin[i];
        int l = (p.x >> 18) & 63;
        int dst = atomicAdd(&pos64[l], 1);
        sout[dst] = make_int2(p.x & 0x3FFFF, p.y);
    }
    __syncthreads();

    for (int i = t; i < cnt; i += 256)
        rec[(size_t)b * CAP + i] = sout[i];

    if (t < 64) {
        int v = cnt64[t];
        int sum = v;
        #pragma unroll
        for (int off = 1; off < 64; off <<= 1) {
            int x = __shfl_up(sum, off, 64);
            if (t >= off) sum += x;
        }
        int start = b * CAP + (sum - v);
        int node = b * 64 + t;
        if (node < N_NODES) range[node] = make_int2(start, start + v);
    }
}

// ---------------------------------------------------------------------------
// side_k: wave-per-node segment-sum, float4-vectorized gathers.
// Lane layout: LPR = DIN/4 lanes cover one row (float4 each); EPW = 64/LPR
// edges are fetched by ONE global_load_dwordx4 (1 KB/instr for D=64).
// Two groups in flight per iteration; masked tails via a=0; cross-group
// shfl_xor reduction at the end.
// ---------------------------------------------------------------------------
template<int DIN, bool CONCAT>
__global__ __launch_bounds__(256)
void side_k(const int2* __restrict__ range,
            const int2* __restrict__ rec,
            const float* __restrict__ ego_in,
            const float* __restrict__ user_emb, const float* __restrict__ ent_emb,
            float* __restrict__ side) {
    constexpr int LPR = DIN / 4;       // lanes per row: 16 (D64), 8 (D32)
    constexpr int EPW = 64 / LPR;      // edges per wave-load: 4 (D64), 8 (D32)

    int w = threadIdx.x >> 6;
    int lane = threadIdx.x & 63;
    int h = blockIdx.x * 4 + w;

    int2 rg = range[h];
    int e0 = rg.x, e1 = rg.y;

    int g = lane / LPR;                // edge subgroup
    int q = lane % LPR;                // col quad

    float4 acc = make_float4(0.f, 0.f, 0.f, 0.f);

    #define ROWP(t) (CONCAT ? (((t) < N_USERS) ? (user_emb + (size_t)(t) * 64) \
                                               : (ent_emb + (size_t)((t) - N_USERS) * 64)) \
                            : (ego_in + (size_t)(t) * DIN))
    for (int e = e0; e < e1; e += 2 * EPW) {
        int i0 = e + g;
        int i1 = e + EPW + g;
        int c0 = i0 < e1 ? i0 : e1 - 1;
        int c1 = i1 < e1 ? i1 : e1 - 1;
        int2 p0 = rec[c0];
        int2 p1 = rec[c1];
        float a0 = (i0 < e1) ? __int_as_float(p0.y) : 0.f;
        float a1 = (i1 < e1) ? __int_as_float(p1.y) : 0.f;
        float4 x0 = *(const float4*)(ROWP(p0.x) + q * 4);
        float4 x1 = *(const float4*)(ROWP(p1.x) + q * 4);
        acc.x = fmaf(a0, x0.x, acc.x);
        acc.y = fmaf(a0, x0.y, acc.y);
        acc.z = fmaf(a0, x0.z, acc.z);
        acc.w = fmaf(a0, x0.w, acc.w);
        acc.x = fmaf(a1, x1.x, acc.x);
        acc.y = fmaf(a1, x1.y, acc.y);
        acc.z = fmaf(a1, x1.z, acc.z);
        acc.w = fmaf(a1, x1.w, acc.w);
    }
    #undef ROWP

    // reduce across edge subgroups (lanes differing above bit log2(LPR))
    #pragma unroll
    for (int off = LPR; off < 64; off <<= 1) {
        acc.x += __shfl_xor(acc.x, off, 64);
        acc.y += __shfl_xor(acc.y, off, 64);
        acc.z += __shfl_xor(acc.z, off, 64);
        acc.w += __shfl_xor(acc.w, off, 64);
    }

    if (lane < LPR)
        *(float4*)(side + (size_t)h * DIN + lane * 4) = acc;
}

// ---------------------------------------------------------------------------
// transform_k: tiled vector GEMM over node rows (unchanged).
// ---------------------------------------------------------------------------
template<int DIN, int DOUT, int TILE_ROWS, bool CONCAT>
__global__ __launch_bounds__(256)
void transform_k(const float* __restrict__ ego_in,
                 const float* __restrict__ user_emb, const float* __restrict__ ent_emb,
                 const float* __restrict__ side,
                 const float* __restrict__ Wgc, const float* __restrict__ bgc,
                 const float* __restrict__ Wbi, const float* __restrict__ bbi,
                 float* __restrict__ ego_out) {
    constexpr int NG = DOUT / 8;
    constexpr int RG = 256 / NG;
    constexpr int RT = TILE_ROWS / RG;
    constexpr int STRIDE = DIN + 4;
    constexpr int KC = DIN / 4;

    __shared__ float sWgc[DIN * DOUT], sWbi[DIN * DOUT];
    __shared__ float sU[TILE_ROWS * STRIDE], sV[TILE_ROWS * STRIDE];

    int t = threadIdx.x;

    for (int i = t * 4; i < DIN * DOUT; i += 1024) {
        *(float4*)&sWgc[i] = *(const float4*)&Wgc[i];
        *(float4*)&sWbi[i] = *(const float4*)&Wbi[i];
    }

    int base = blockIdx.x * TILE_ROWS;
    for (int f = t; f < TILE_ROWS * KC; f += 256) {
        int row = f / KC, kc = f % KC;
        int n = base + row;
        int nc = n < N_NODES ? n : N_NODES - 1;
        const float* erow;
        if (CONCAT) {
            erow = (nc < N_USERS) ? user_emb + (size_t)nc * 64
                                  : ent_emb + (size_t)(nc - N_USERS) * 64;
        } else {
            erow = ego_in + (size_t)nc * DIN;
        }
        float4 e4 = ((const float4*)erow)[kc];
        float4 s4 = ((const float4*)(side + (size_t)nc * DIN))[kc];
        float4 u4, v4;
        u4.x = e4.x + s4.x; u4.y = e4.y + s4.y; u4.z = e4.z + s4.z; u4.w = e4.w + s4.w;
        v4.x = e4.x * s4.x; v4.y = e4.y * s4.y; v4.z = e4.z * s4.z; v4.w = e4.w * s4.w;
        *(float4*)&sU[row * STRIDE + kc * 4] = u4;
        *(float4*)&sV[row * STRIDE + kc * 4] = v4;
    }
    __syncthreads();

    int cg = t % NG, rg = t / NG;
    int c0 = cg * 8;
    int r0 = rg * RT;

    float accg[RT][8], accb[RT][8];
    #pragma unroll
    for (int r = 0; r < RT; ++r)
        #pragma unroll
        for (int j = 0; j < 8; ++j) { accg[r][j] = 0.f; accb[r][j] = 0.f; }

    for (int k = 0; k < DIN; k += 4) {
        float4 u4[RT], v4[RT];
        #pragma unroll
        for (int r = 0; r < RT; ++r) {
            u4[r] = *(const float4*)&sU[(r0 + r) * STRIDE + k];
            v4[r] = *(const float4*)&sV[(r0 + r) * STRIDE + k];
        }
        #pragma unroll
        for (int kk = 0; kk < 4; ++kk) {
            float4 wg0 = *(const float4*)&sWgc[(k + kk) * DOUT + c0];
            float4 wg1 = *(const float4*)&sWgc[(k + kk) * DOUT + c0 + 4];
            float4 wb0 = *(const float4*)&sWbi[(k + kk) * DOUT + c0];
            float4 wb1 = *(const float4*)&sWbi[(k + kk) * DOUT + c0 + 4];
            #pragma unroll
            for (int r = 0; r < RT; ++r) {
                float u = ((const float*)&u4[r])[kk];
                float v = ((const float*)&v4[r])[kk];
                accg[r][0] = fmaf(u, wg0.x, accg[r][0]);
                accg[r][1] = fmaf(u, wg0.y, accg[r][1]);
                accg[r][2] = fmaf(u, wg0.z, accg[r][2]);
                accg[r][3] = fmaf(u, wg0.w, accg[r][3]);
                accg[r][4] = fmaf(u, wg1.x, accg[r][4]);
                accg[r][5] = fmaf(u, wg1.y, accg[r][5]);
                accg[r][6] = fmaf(u, wg1.z, accg[r][6]);
                accg[r][7] = fmaf(u, wg1.w, accg[r][7]);
                accb[r][0] = fmaf(v, wb0.x, accb[r][0]);
                accb[r][1] = fmaf(v, wb0.y, accb[r][1]);
                accb[r][2] = fmaf(v, wb0.z, accb[r][2]);
                accb[r][3] = fmaf(v, wb0.w, accb[r][3]);
                accb[r][4] = fmaf(v, wb1.x, accb[r][4]);
                accb[r][5] = fmaf(v, wb1.y, accb[r][5]);
                accb[r][6] = fmaf(v, wb1.z, accb[r][6]);
                accb[r][7] = fmaf(v, wb1.w, accb[r][7]);
            }
        }
    }

    float4 bg0 = *(const float4*)&bgc[c0];
    float4 bg1 = *(const float4*)&bgc[c0 + 4];
    float4 bb0 = *(const float4*)&bbi[c0];
    float4 bb1 = *(const float4*)&bbi[c0 + 4];
    float bg[8] = {bg0.x, bg0.y, bg0.z, bg0.w, bg1.x, bg1.y, bg1.z, bg1.w};
    float bb[8] = {bb0.x, bb0.y, bb0.z, bb0.w, bb1.x, bb1.y, bb1.z, bb1.w};

    #pragma unroll
    for (int r = 0; r < RT; ++r) {
        int n = base + r0 + r;
        if (n < N_NODES) {
            float o[8];
            #pragma unroll
            for (int j = 0; j < 8; ++j) {
                float g = accg[r][j] + bg[j];
                float b2 = accb[r][j] + bb[j];
                g = g > 0.f ? g : SLOPE * g;
                b2 = b2 > 0.f ? b2 : SLOPE * b2;
                o[j] = g + b2;
            }
            float* dst = ego_out + (size_t)n * DOUT + c0;
            *(float4*)dst       = make_float4(o[0], o[1], o[2], o[3]);
            *(float4*)(dst + 4) = make_float4(o[4], o[5], o[6], o[7]);
        }
    }
}

// ---------------------------------------------------------------------------
// Gather: out rows = [ego0(64) | norm(ego1)(64) | norm(ego2)(32) | norm(ego3)(16)]
// ---------------------------------------------------------------------------
__global__ __launch_bounds__(64)
void gather_k(const int* __restrict__ users, const int* __restrict__ pos,
              const int* __restrict__ neg,
              const float* __restrict__ user_emb, const float* __restrict__ ent_emb,
              const float* __restrict__ ego1, const float* __restrict__ ego2,
              const float* __restrict__ ego3,
              float* __restrict__ out) {
    int r = blockIdx.x;
    int lane = threadIdx.x;
    int which = r / BATCH;
    int i = r - which * BATCH;
    int node;
    if (which == 0)      node = users[i];
    else if (which == 1) node = N_USERS + pos[i];
    else                 node = N_USERS + neg[i];

    float* o = out + (size_t)r * 176;

    float x0 = (node < N_USERS) ? user_emb[(size_t)node * 64 + lane]
                                : ent_emb[(size_t)(node - N_USERS) * 64 + lane];
    o[lane] = x0;

    float x1 = ego1[(size_t)node * 64 + lane];
    float ss = x1 * x1;
    #pragma unroll
    for (int off = 32; off > 0; off >>= 1) ss += __shfl_xor(ss, off, 64);
    o[64 + lane] = x1 / fmaxf(sqrtf(ss), EPSF);

    float x2 = (lane < 32) ? ego2[(size_t)node * 32 + lane] : 0.f;
    float ss2 = x2 * x2;
    #pragma unroll
    for (int off = 32; off > 0; off >>= 1) ss2 += __shfl_xor(ss2, off, 64);
    if (lane < 32) o[128 + lane] = x2 / fmaxf(sqrtf(ss2), EPSF);

    float x3 = (lane < 16) ? ego3[(size_t)node * 16 + lane] : 0.f;
    float ss3 = x3 * x3;
    #pragma unroll
    for (int off = 32; off > 0; off >>= 1) ss3 += __shfl_xor(ss3, off, 64);
    if (lane < 16) o[160 + lane] = x3 / fmaxf(sqrtf(ss3), EPSF);
}

// ---------------------------------------------------------------------------
extern "C" void kernel_launch(void* const* d_in, const int* in_sizes, int n_in,
                              void* d_out, int out_size, void* d_ws, size_t ws_size,
                              hipStream_t stream) {
    const int*   users    = (const int*)d_in[0];
    const int*   pos      = (const int*)d_in[1];
    const int*   neg      = (const int*)d_in[2];
    const int*   all_h    = (const int*)d_in[3];
    const int*   all_t    = (const int*)d_in[4];
    const float* A        = (const float*)d_in[5];
    const float* user_emb = (const float*)d_in[6];
    const float* ent_emb  = (const float*)d_in[7];
    const float* Wgc0 = (const float*)d_in[8];
    const float* bgc0 = (const float*)d_in[9];
    const float* Wbi0 = (const float*)d_in[10];
    const float* bbi0 = (const float*)d_in[11];
    const float* Wgc1 = (const float*)d_in[12];
    const float* bgc1 = (const float*)d_in[13];
    const float* Wbi1 = (const float*)d_in[14];
    const float* bbi1 = (const float*)d_in[15];
    const float* Wgc2 = (const float*)d_in[16];
    const float* bgc2 = (const float*)d_in[17];
    const float* Wbi2 = (const float*)d_in[18];
    const float* bbi2 = (const float*)d_in[19];

    // ---- workspace carve-up (256B-aligned). rec dead after L2's side pass,
    // ego3 aliases its head.
    char* p = (char*)d_ws;
    int*   gcursor = (int*)p;    p += ((size_t)NBUK * 4 + 255) & ~255ull;
    int2*  rec     = (int2*)p;   char* rec_base = p;
    p += ((size_t)NBUK * CAP * 8 + 255) & ~255ull;
    int2*  range   = (int2*)p;   p += ((size_t)N_NODES * 8 + 255) & ~255ull;
    float* side    = (float*)p;  p += ((size_t)N_NODES * 64 * 4 + 255) & ~255ull;
    float* ego1    = (float*)p;  p += ((size_t)N_NODES * 64 * 4 + 255) & ~255ull;
    float* ego2    = (float*)p;  p += ((size_t)N_NODES * 32 * 4 + 255) & ~255ull;
    float* ego3    = (float*)rec_base;   // aliases rec (dead by then)
    float* out     = (float*)d_out;

    const int nodeBlocks = N_NODES / 4;

    // ---- bucket partition + per-bucket local sort (once) ----
    (void)hipMemsetAsync(gcursor, 0, (size_t)NBUK * 4, stream);
    partition_k<<<NPB, 256, 0, stream>>>(all_h, all_t, A, gcursor, rec);
    local_sort_k<<<NBUK, 256, 0, stream>>>(gcursor, rec, range);

    // ---- layer 0: 64 -> 64 ----
    side_k<64, true><<<nodeBlocks, 256, 0, stream>>>(
        range, rec, nullptr, user_emb, ent_emb, side);
    transform_k<64, 64, 64, true><<<(N_NODES + 63) / 64, 256, 0, stream>>>(
        nullptr, user_emb, ent_emb, side, Wgc0, bgc0, Wbi0, bbi0, ego1);

    // ---- layer 1: 64 -> 32 ----
    side_k<64, false><<<nodeBlocks, 256, 0, stream>>>(
        range, rec, ego1, nullptr, nullptr, side);
    transform_k<64, 32, 64, false><<<(N_NODES + 63) / 64, 256, 0, stream>>>(
        ego1, nullptr, nullptr, side, Wgc1, bgc1, Wbi1, bbi1, ego2);

    // ---- layer 2: 32 -> 16 ----
    side_k<32, false><<<nodeBlocks, 256, 0, stream>>>(
        range, rec, ego2, nullptr, nullptr, side);
    transform_k<32, 16, 128, false><<<(N_NODES + 127) / 128, 256, 0, stream>>>(
        ego2, nullptr, nullptr, side, Wgc2, bgc2, Wbi2, bbi2, ego3);

    // ---- final gather + lazy normalization ----
    gather_k<<<3 * BATCH, 64, 0, stream>>>(
        users, pos, neg, user_emb, ent_emb, ego1, ego2, ego3, out);
}

// Round 11
// 529.872 us; speedup vs baseline: 5.7455x; 1.1542x over previous
//
#include <hip/hip_runtime.h>
#include <math.h>

#define N_USERS    50000
#define N_ENTITIES 100000
#define N_NODES    150000
#define N_EDGES    3000000
#define BATCH      8192
#define SLOPE      0.2f
#define EPSF       1e-12f

// bucket partition: bucket = h>>6 (64 nodes per bucket)
#define NBUK   2344            // ceil(150000/64)
#define CAP    1536            // per-bucket capacity (mean 1280, sd 36: +7.1 sd)
#define BLK_E  8192
#define NPB    ((N_EDGES + BLK_E - 1) / BLK_E)   // 367

__device__ __forceinline__ unsigned f2bf(float f) {       // RNE fp32->bf16
    unsigned u = __float_as_uint(f);
    return (u + 0x7FFFu + ((u >> 16) & 1u)) >> 16;
}
__device__ __forceinline__ float bf_lo(unsigned d) { return __uint_as_float(d << 16); }
__device__ __forceinline__ float bf_hi(unsigned d) { return __uint_as_float(d & 0xFFFF0000u); }

// ---------------------------------------------------------------------------
// cast0_k: concat(user_emb, ent_emb) -> bf16 table (150000 x 64)
// ---------------------------------------------------------------------------
__global__ __launch_bounds__(256)
void cast0_k(const float* __restrict__ user_emb, const float* __restrict__ ent_emb,
             unsigned short* __restrict__ ego0_bf) {
    int idx = blockIdx.x * 256 + threadIdx.x;
    const int total = N_NODES * 64 / 4;
    if (idx >= total) return;
    int ge = idx * 4;
    const float* src = (ge < N_USERS * 64) ? user_emb + ge
                                           : ent_emb + (ge - N_USERS * 64);
    float4 v = *(const float4*)src;
    ushort4 o;
    o.x = (unsigned short)f2bf(v.x);
    o.y = (unsigned short)f2bf(v.y);
    o.z = (unsigned short)f2bf(v.z);
    o.w = (unsigned short)f2bf(v.w);
    *(ushort4*)(ego0_bf + ge) = o;
}

// ---------------------------------------------------------------------------
// partition_k: single-pass bucket scatter. Record: {t | (h&63)<<18, bits(a)}.
// ---------------------------------------------------------------------------
__global__ __launch_bounds__(256)
void partition_k(const int* __restrict__ all_h, const int* __restrict__ all_t,
                 const float* __restrict__ A,
                 int* __restrict__ gcursor, int2* __restrict__ rec) {
    __shared__ int hist[NBUK];
    __shared__ int cnt2[NBUK];
    int t = threadIdx.x;
    for (int i = t; i < NBUK; i += 256) { hist[i] = 0; cnt2[i] = 0; }
    __syncthreads();

    int e0 = blockIdx.x * BLK_E;
    int e1 = e0 + BLK_E; if (e1 > N_EDGES) e1 = N_EDGES;

    for (int e = e0 + t; e < e1; e += 256)
        atomicAdd(&hist[all_h[e] >> 6], 1);
    __syncthreads();

    for (int i = t; i < NBUK; i += 256) {
        int c = hist[i];
        hist[i] = c ? atomicAdd(&gcursor[i], c) : 0;
    }
    __syncthreads();

    for (int e = e0 + t; e < e1; e += 256) {
        int h = all_h[e];
        int b = h >> 6;
        int r = hist[b] + atomicAdd(&cnt2[b], 1);
        if (r < CAP)
            rec[(size_t)b * CAP + r] =
                make_int2(all_t[e] | ((h & 63) << 18), __float_as_int(A[e]));
    }
}

// ---------------------------------------------------------------------------
// local_sort_k: per-bucket 64-bin counting sort in LDS -> h-grouped records
// + per-node (start,end) ranges.
// ---------------------------------------------------------------------------
__global__ __launch_bounds__(256)
void local_sort_k(const int* __restrict__ gcursor, int2* __restrict__ rec,
                  int2* __restrict__ range) {
    __shared__ int2 sin[CAP];
    __shared__ int2 sout[CAP];
    __shared__ int cnt64[64];
    __shared__ int pos64[64];
    int b = blockIdx.x, t = threadIdx.x;
    int cnt = gcursor[b]; if (cnt > CAP) cnt = CAP;

    if (t < 64) cnt64[t] = 0;
    __syncthreads();

    for (int i = t; i < cnt; i += 256) {
        int2 p = rec[(size_t)b * CAP + i];
        sin[i] = p;
        atomicAdd(&cnt64[(p.x >> 18) & 63], 1);
    }
    __syncthreads();

    if (t < 64) {
        int v = cnt64[t];
        int sum = v;
        #pragma unroll
        for (int off = 1; off < 64; off <<= 1) {
            int x = __shfl_up(sum, off, 64);
            if (t >= off) sum += x;
        }
        pos64[t] = sum - v;
    }
    __syncthreads();

    for (int i = t; i < cnt; i += 256) {
        int2 p = sin[i];
        int l = (p.x >> 18) & 63;
        int dst = atomicAdd(&pos64[l], 1);
        sout[dst] = make_int2(p.x & 0x3FFFF, p.y);
    }
    __syncthreads();

    for (int i = t; i < cnt; i += 256)
        rec[(size_t)b * CAP + i] = sout[i];

    if (t < 64) {
        int v = cnt64[t];
        int sum = v;
        #pragma unroll
        for (int off = 1; off < 64; off <<= 1) {
            int x = __shfl_up(sum, off, 64);
            if (t >= off) sum += x;
        }
        int start = b * CAP + (sum - v);
        int node = b * 64 + t;
        if (node < N_NODES) range[node] = make_int2(start, start + v);
    }
}

// ---------------------------------------------------------------------------
// side_k: wave-per-node segment-sum over bf16 rows.
// LPR = DIN/8 lanes cover one row (uint4 = 8 bf16 each); EPW = 64/LPR edges
// per wave-load. fp32 accumulate; cross-group shfl reduction; fp32 side out.
// ---------------------------------------------------------------------------
template<int DIN>
__global__ __launch_bounds__(256)
void side_k(const int2* __restrict__ range, const int2* __restrict__ rec,
            const unsigned short* __restrict__ tab, float* __restrict__ side) {
    constexpr int LPR = DIN / 8;       // 8 (D64), 4 (D32)
    constexpr int EPW = 64 / LPR;      // 8 (D64), 16 (D32)

    int w = threadIdx.x >> 6;
    int lane = threadIdx.x & 63;
    int h = blockIdx.x * 4 + w;

    int2 rg = range[h];
    int e0 = rg.x, e1 = rg.y;
    int g = lane / LPR;
    int q = lane % LPR;

    float acc[8];
    #pragma unroll
    for (int j = 0; j < 8; ++j) acc[j] = 0.f;

    for (int e = e0; e < e1; e += 2 * EPW) {
        int i0 = e + g;
        int i1 = e + EPW + g;
        int c0 = i0 < e1 ? i0 : e1 - 1;
        int c1 = i1 < e1 ? i1 : e1 - 1;
        int2 p0 = rec[c0];
        int2 p1 = rec[c1];
        float a0 = (i0 < e1) ? __int_as_float(p0.y) : 0.f;
        float a1 = (i1 < e1) ? __int_as_float(p1.y) : 0.f;
        uint4 d0 = *(const uint4*)(tab + (size_t)p0.x * DIN + q * 8);
        uint4 d1 = *(const uint4*)(tab + (size_t)p1.x * DIN + q * 8);
        acc[0] = fmaf(a0, bf_lo(d0.x), acc[0]);
        acc[1] = fmaf(a0, bf_hi(d0.x), acc[1]);
        acc[2] = fmaf(a0, bf_lo(d0.y), acc[2]);
        acc[3] = fmaf(a0, bf_hi(d0.y), acc[3]);
        acc[4] = fmaf(a0, bf_lo(d0.z), acc[4]);
        acc[5] = fmaf(a0, bf_hi(d0.z), acc[5]);
        acc[6] = fmaf(a0, bf_lo(d0.w), acc[6]);
        acc[7] = fmaf(a0, bf_hi(d0.w), acc[7]);
        acc[0] = fmaf(a1, bf_lo(d1.x), acc[0]);
        acc[1] = fmaf(a1, bf_hi(d1.x), acc[1]);
        acc[2] = fmaf(a1, bf_lo(d1.y), acc[2]);
        acc[3] = fmaf(a1, bf_hi(d1.y), acc[3]);
        acc[4] = fmaf(a1, bf_lo(d1.z), acc[4]);
        acc[5] = fmaf(a1, bf_hi(d1.z), acc[5]);
        acc[6] = fmaf(a1, bf_lo(d1.w), acc[6]);
        acc[7] = fmaf(a1, bf_hi(d1.w), acc[7]);
    }

    #pragma unroll
    for (int off = LPR; off < 64; off <<= 1)
        #pragma unroll
        for (int j = 0; j < 8; ++j) acc[j] += __shfl_xor(acc[j], off, 64);

    if (lane < LPR) {
        float* dst = side + (size_t)h * DIN + q * 8;
        *(float4*)dst       = make_float4(acc[0], acc[1], acc[2], acc[3]);
        *(float4*)(dst + 4) = make_float4(acc[4], acc[5], acc[6], acc[7]);
    }
}

// ---------------------------------------------------------------------------
// transform_k: tiled vector GEMM. ego_in is bf16 (or fp32 user/ent when
// CONCAT). Output bf16 (OUT_BF) or fp32.
// ---------------------------------------------------------------------------
template<int DIN, int DOUT, int TILE_ROWS, bool CONCAT, bool OUT_BF>
__global__ __launch_bounds__(256)
void transform_k(const unsigned short* __restrict__ ego_in,
                 const float* __restrict__ user_emb, const float* __restrict__ ent_emb,
                 const float* __restrict__ side,
                 const float* __restrict__ Wgc, const float* __restrict__ bgc,
                 const float* __restrict__ Wbi, const float* __restrict__ bbi,
                 void* __restrict__ ego_out) {
    constexpr int NG = DOUT / 8;
    constexpr int RG = 256 / NG;
    constexpr int RT = TILE_ROWS / RG;
    constexpr int STRIDE = DIN + 4;
    constexpr int KC8 = DIN / 8;

    __shared__ float sWgc[DIN * DOUT], sWbi[DIN * DOUT];
    __shared__ float sU[TILE_ROWS * STRIDE], sV[TILE_ROWS * STRIDE];

    int t = threadIdx.x;

    for (int i = t * 4; i < DIN * DOUT; i += 1024) {
        *(float4*)&sWgc[i] = *(const float4*)&Wgc[i];
        *(float4*)&sWbi[i] = *(const float4*)&Wbi[i];
    }

    int base = blockIdx.x * TILE_ROWS;
    for (int f = t; f < TILE_ROWS * KC8; f += 256) {
        int row = f / KC8, c8 = f % KC8;
        int n = base + row;
        int nc = n < N_NODES ? n : N_NODES - 1;
        float ev[8];
        if (CONCAT) {
            const float* erow = (nc < N_USERS) ? user_emb + (size_t)nc * 64
                                               : ent_emb + (size_t)(nc - N_USERS) * 64;
            float4 a = *(const float4*)(erow + c8 * 8);
            float4 b = *(const float4*)(erow + c8 * 8 + 4);
            ev[0] = a.x; ev[1] = a.y; ev[2] = a.z; ev[3] = a.w;
            ev[4] = b.x; ev[5] = b.y; ev[6] = b.z; ev[7] = b.w;
        } else {
            uint4 d = *(const uint4*)(ego_in + (size_t)nc * DIN + c8 * 8);
            ev[0] = bf_lo(d.x); ev[1] = bf_hi(d.x);
            ev[2] = bf_lo(d.y); ev[3] = bf_hi(d.y);
            ev[4] = bf_lo(d.z); ev[5] = bf_hi(d.z);
            ev[6] = bf_lo(d.w); ev[7] = bf_hi(d.w);
        }
        const float* srow = side + (size_t)nc * DIN + c8 * 8;
        float4 s0 = *(const float4*)srow;
        float4 s1 = *(const float4*)(srow + 4);
        float sv8[8] = {s0.x, s0.y, s0.z, s0.w, s1.x, s1.y, s1.z, s1.w};
        float* pu = &sU[row * STRIDE + c8 * 8];
        float* pv = &sV[row * STRIDE + c8 * 8];
        *(float4*)pu       = make_float4(ev[0] + sv8[0], ev[1] + sv8[1], ev[2] + sv8[2], ev[3] + sv8[3]);
        *(float4*)(pu + 4) = make_float4(ev[4] + sv8[4], ev[5] + sv8[5], ev[6] + sv8[6], ev[7] + sv8[7]);
        *(float4*)pv       = make_float4(ev[0] * sv8[0], ev[1] * sv8[1], ev[2] * sv8[2], ev[3] * sv8[3]);
        *(float4*)(pv + 4) = make_float4(ev[4] * sv8[4], ev[5] * sv8[5], ev[6] * sv8[6], ev[7] * sv8[7]);
    }
    __syncthreads();

    int cg = t % NG, rgi = t / NG;
    int c0 = cg * 8;
    int r0 = rgi * RT;

    float accg[RT][8], accb[RT][8];
    #pragma unroll
    for (int r = 0; r < RT; ++r)
        #pragma unroll
        for (int j = 0; j < 8; ++j) { accg[r][j] = 0.f; accb[r][j] = 0.f; }

    for (int k = 0; k < DIN; k += 4) {
        float4 u4[RT], v4[RT];
        #pragma unroll
        for (int r = 0; r < RT; ++r) {
            u4[r] = *(const float4*)&sU[(r0 + r) * STRIDE + k];
            v4[r] = *(const float4*)&sV[(r0 + r) * STRIDE + k];
        }
        #pragma unroll
        for (int kk = 0; kk < 4; ++kk) {
            float4 wg0 = *(const float4*)&sWgc[(k + kk) * DOUT + c0];
            float4 wg1 = *(const float4*)&sWgc[(k + kk) * DOUT + c0 + 4];
            float4 wb0 = *(const float4*)&sWbi[(k + kk) * DOUT + c0];
            float4 wb1 = *(const float4*)&sWbi[(k + kk) * DOUT + c0 + 4];
            #pragma unroll
            for (int r = 0; r < RT; ++r) {
                float u = ((const float*)&u4[r])[kk];
                float v = ((const float*)&v4[r])[kk];
                accg[r][0] = fmaf(u, wg0.x, accg[r][0]);
                accg[r][1] = fmaf(u, wg0.y, accg[r][1]);
                accg[r][2] = fmaf(u, wg0.z, accg[r][2]);
                accg[r][3] = fmaf(u, wg0.w, accg[r][3]);
                accg[r][4] = fmaf(u, wg1.x, accg[r][4]);
                accg[r][5] = fmaf(u, wg1.y, accg[r][5]);
                accg[r][6] = fmaf(u, wg1.z, accg[r][6]);
                accg[r][7] = fmaf(u, wg1.w, accg[r][7]);
                accb[r][0] = fmaf(v, wb0.x, accb[r][0]);
                accb[r][1] = fmaf(v, wb0.y, accb[r][1]);
                accb[r][2] = fmaf(v, wb0.z, accb[r][2]);
                accb[r][3] = fmaf(v, wb0.w, accb[r][3]);
                accb[r][4] = fmaf(v, wb1.x, accb[r][4]);
                accb[r][5] = fmaf(v, wb1.y, accb[r][5]);
                accb[r][6] = fmaf(v, wb1.z, accb[r][6]);
                accb[r][7] = fmaf(v, wb1.w, accb[r][7]);
            }
        }
    }

    float4 bg0 = *(const float4*)&bgc[c0];
    float4 bg1 = *(const float4*)&bgc[c0 + 4];
    float4 bb0 = *(const float4*)&bbi[c0];
    float4 bb1 = *(const float4*)&bbi[c0 + 4];
    float bg[8] = {bg0.x, bg0.y, bg0.z, bg0.w, bg1.x, bg1.y, bg1.z, bg1.w};
    float bb[8] = {bb0.x, bb0.y, bb0.z, bb0.w, bb1.x, bb1.y, bb1.z, bb1.w};

    #pragma unroll
    for (int r = 0; r < RT; ++r) {
        int n = base + r0 + r;
        if (n < N_NODES) {
            float o[8];
            #pragma unroll
            for (int j = 0; j < 8; ++j) {
                float gg = accg[r][j] + bg[j];
                float b2 = accb[r][j] + bb[j];
                gg = gg > 0.f ? gg : SLOPE * gg;
                b2 = b2 > 0.f ? b2 : SLOPE * b2;
                o[j] = gg + b2;
            }
            if (OUT_BF) {
                unsigned short* dst = (unsigned short*)ego_out + (size_t)n * DOUT + c0;
                uint4 wv;
                wv.x = f2bf(o[0]) | (f2bf(o[1]) << 16);
                wv.y = f2bf(o[2]) | (f2bf(o[3]) << 16);
                wv.z = f2bf(o[4]) | (f2bf(o[5]) << 16);
                wv.w = f2bf(o[6]) | (f2bf(o[7]) << 16);
                *(uint4*)dst = wv;
            } else {
                float* dst = (float*)ego_out + (size_t)n * DOUT + c0;
                *(float4*)dst       = make_float4(o[0], o[1], o[2], o[3]);
                *(float4*)(dst + 4) = make_float4(o[4], o[5], o[6], o[7]);
            }
        }
    }
}

// ---------------------------------------------------------------------------
// Gather: out rows = [ego0(64) | norm(ego1)(64) | norm(ego2)(32) | norm(ego3)(16)]
// ego1/ego2 read from bf16 tables; ego0 from fp32 embeds; ego3 fp32.
// ---------------------------------------------------------------------------
__global__ __launch_bounds__(64)
void gather_k(const int* __restrict__ users, const int* __restrict__ pos,
              const int* __restrict__ neg,
              const float* __restrict__ user_emb, const float* __restrict__ ent_emb,
              const unsigned short* __restrict__ ego1_bf,
              const unsigned short* __restrict__ ego2_bf,
              const float* __restrict__ ego3,
              float* __restrict__ out) {
    int r = blockIdx.x;
    int lane = threadIdx.x;
    int which = r / BATCH;
    int i = r - which * BATCH;
    int node;
    if (which == 0)      node = users[i];
    else if (which == 1) node = N_USERS + pos[i];
    else                 node = N_USERS + neg[i];

    float* o = out + (size_t)r * 176;

    float x0 = (node < N_USERS) ? user_emb[(size_t)node * 64 + lane]
                                : ent_emb[(size_t)(node - N_USERS) * 64 + lane];
    o[lane] = x0;

    float x1 = __uint_as_float((unsigned)ego1_bf[(size_t)node * 64 + lane] << 16);
    float ss = x1 * x1;
    #pragma unroll
    for (int off = 32; off > 0; off >>= 1) ss += __shfl_xor(ss, off, 64);
    o[64 + lane] = x1 / fmaxf(sqrtf(ss), EPSF);

    float x2 = (lane < 32)
        ? __uint_as_float((unsigned)ego2_bf[(size_t)node * 32 + lane] << 16) : 0.f;
    float ss2 = x2 * x2;
    #pragma unroll
    for (int off = 32; off > 0; off >>= 1) ss2 += __shfl_xor(ss2, off, 64);
    if (lane < 32) o[128 + lane] = x2 / fmaxf(sqrtf(ss2), EPSF);

    float x3 = (lane < 16) ? ego3[(size_t)node * 16 + lane] : 0.f;
    float ss3 = x3 * x3;
    #pragma unroll
    for (int off = 32; off > 0; off >>= 1) ss3 += __shfl_xor(ss3, off, 64);
    if (lane < 16) o[160 + lane] = x3 / fmaxf(sqrtf(ss3), EPSF);
}

// ---------------------------------------------------------------------------
extern "C" void kernel_launch(void* const* d_in, const int* in_sizes, int n_in,
                              void* d_out, int out_size, void* d_ws, size_t ws_size,
                              hipStream_t stream) {
    const int*   users    = (const int*)d_in[0];
    const int*   pos      = (const int*)d_in[1];
    const int*   neg      = (const int*)d_in[2];
    const int*   all_h    = (const int*)d_in[3];
    const int*   all_t    = (const int*)d_in[4];
    const float* A        = (const float*)d_in[5];
    const float* user_emb = (const float*)d_in[6];
    const float* ent_emb  = (const float*)d_in[7];
    const float* Wgc0 = (const float*)d_in[8];
    const float* bgc0 = (const float*)d_in[9];
    const float* Wbi0 = (const float*)d_in[10];
    const float* bbi0 = (const float*)d_in[11];
    const float* Wgc1 = (const float*)d_in[12];
    const float* bgc1 = (const float*)d_in[13];
    const float* Wbi1 = (const float*)d_in[14];
    const float* bbi1 = (const float*)d_in[15];
    const float* Wgc2 = (const float*)d_in[16];
    const float* bgc2 = (const float*)d_in[17];
    const float* Wbi2 = (const float*)d_in[18];
    const float* bbi2 = (const float*)d_in[19];

    // ---- workspace (256B-aligned). rec dead after side L2 -> ego3 aliases.
    char* p = (char*)d_ws;
    int*   gcursor = (int*)p;            p += ((size_t)NBUK * 4 + 255) & ~255ull;
    int2*  rec     = (int2*)p;           char* rec_base = p;
    p += ((size_t)NBUK * CAP * 8 + 255) & ~255ull;
    int2*  range   = (int2*)p;           p += ((size_t)N_NODES * 8 + 255) & ~255ull;
    float* side    = (float*)p;          p += ((size_t)N_NODES * 64 * 4 + 255) & ~255ull;
    unsigned short* ego0_bf = (unsigned short*)p; p += ((size_t)N_NODES * 64 * 2 + 255) & ~255ull;
    unsigned short* ego1_bf = (unsigned short*)p; p += ((size_t)N_NODES * 64 * 2 + 255) & ~255ull;
    unsigned short* ego2_bf = (unsigned short*)p; p += ((size_t)N_NODES * 32 * 2 + 255) & ~255ull;
    float* ego3    = (float*)rec_base;   // aliases rec (dead by then)
    float* out     = (float*)d_out;

    const int nodeBlocks = N_NODES / 4;

    // ---- prep: bf16 concat table + bucket partition + local sort ----
    (void)hipMemsetAsync(gcursor, 0, (size_t)NBUK * 4, stream);
    cast0_k<<<(N_NODES * 64 / 4 + 255) / 256, 256, 0, stream>>>(user_emb, ent_emb, ego0_bf);
    partition_k<<<NPB, 256, 0, stream>>>(all_h, all_t, A, gcursor, rec);
    local_sort_k<<<NBUK, 256, 0, stream>>>(gcursor, rec, range);

    // ---- layer 0: 64 -> 64 ----
    side_k<64><<<nodeBlocks, 256, 0, stream>>>(range, rec, ego0_bf, side);
    transform_k<64, 64, 64, true, true><<<(N_NODES + 63) / 64, 256, 0, stream>>>(
        nullptr, user_emb, ent_emb, side, Wgc0, bgc0, Wbi0, bbi0, ego1_bf);

    // ---- layer 1: 64 -> 32 ----
    side_k<64><<<nodeBlocks, 256, 0, stream>>>(range, rec, ego1_bf, side);
    transform_k<64, 32, 64, false, true><<<(N_NODES + 63) / 64, 256, 0, stream>>>(
        ego1_bf, nullptr, nullptr, side, Wgc1, bgc1, Wbi1, bbi1, ego2_bf);

    // ---- layer 2: 32 -> 16 ----
    side_k<32><<<nodeBlocks, 256, 0, stream>>>(range, rec, ego2_bf, side);
    transform_k<32, 16, 128, false, false><<<(N_NODES + 127) / 128, 256, 0, stream>>>(
        ego2_bf, nullptr, nullptr, side, Wgc2, bgc2, Wbi2, bbi2, ego3);

    // ---- final gather + lazy normalization ----
    gather_k<<<3 * BATCH, 64, 0, stream>>>(
        users, pos, neg, user_emb, ent_emb, ego1_bf, ego2_bf, ego3, out);
}

// Round 12
// 515.244 us; speedup vs baseline: 5.9086x; 1.0284x over previous
//
#include <hip/hip_runtime.h>
#include <math.h>

#define N_USERS    50000
#define N_ENTITIES 100000
#define N_NODES    150000
#define N_EDGES    3000000
#define BATCH      8192
#define SLOPE      0.2f
#define EPSF       1e-12f

// bucket partition: bucket = h>>6 (64 nodes per bucket)
#define NBUK   2344            // ceil(150000/64)
#define CAP    1536            // per-bucket capacity (mean 1280, sd 36: +7.1 sd)
#define BLK_E  8192
#define NPB    ((N_EDGES + BLK_E - 1) / BLK_E)   // 367
#define PBLK   1024            // partition block size (16 waves for latency hiding)

__device__ __forceinline__ unsigned f2bf(float f) {       // RNE fp32->bf16
    unsigned u = __float_as_uint(f);
    return (u + 0x7FFFu + ((u >> 16) & 1u)) >> 16;
}
__device__ __forceinline__ float bf_lo(unsigned d) { return __uint_as_float(d << 16); }
__device__ __forceinline__ float bf_hi(unsigned d) { return __uint_as_float(d & 0xFFFF0000u); }

// ---------------------------------------------------------------------------
// cast0_k: concat(user_emb, ent_emb) -> bf16 table (150000 x 64)
// ---------------------------------------------------------------------------
__global__ __launch_bounds__(256)
void cast0_k(const float* __restrict__ user_emb, const float* __restrict__ ent_emb,
             unsigned short* __restrict__ ego0_bf) {
    int idx = blockIdx.x * 256 + threadIdx.x;
    const int total = N_NODES * 64 / 4;
    if (idx >= total) return;
    int ge = idx * 4;
    const float* src = (ge < N_USERS * 64) ? user_emb + ge
                                           : ent_emb + (ge - N_USERS * 64);
    float4 v = *(const float4*)src;
    ushort4 o;
    o.x = (unsigned short)f2bf(v.x);
    o.y = (unsigned short)f2bf(v.y);
    o.z = (unsigned short)f2bf(v.z);
    o.w = (unsigned short)f2bf(v.w);
    *(ushort4*)(ego0_bf + ge) = o;
}

// ---------------------------------------------------------------------------
// partition_k: single-pass bucket scatter. Record: {t | (h&63)<<18, bits(a)}.
// 1024-thread blocks: 16 waves/block for latency hiding (R11 showed 12.5%
// occupancy with 256-thread blocks -> latency-starved).
// ---------------------------------------------------------------------------
__global__ __launch_bounds__(PBLK)
void partition_k(const int* __restrict__ all_h, const int* __restrict__ all_t,
                 const float* __restrict__ A,
                 int* __restrict__ gcursor, int2* __restrict__ rec) {
    __shared__ int hist[NBUK];
    __shared__ int cnt2[NBUK];
    int t = threadIdx.x;
    for (int i = t; i < NBUK; i += PBLK) { hist[i] = 0; cnt2[i] = 0; }
    __syncthreads();

    int e0 = blockIdx.x * BLK_E;
    int e1 = e0 + BLK_E; if (e1 > N_EDGES) e1 = N_EDGES;

    for (int e = e0 + t; e < e1; e += PBLK)
        atomicAdd(&hist[all_h[e] >> 6], 1);
    __syncthreads();

    for (int i = t; i < NBUK; i += PBLK) {
        int c = hist[i];
        hist[i] = c ? atomicAdd(&gcursor[i], c) : 0;
    }
    __syncthreads();

    for (int e = e0 + t; e < e1; e += PBLK) {
        int h = all_h[e];
        int b = h >> 6;
        int r = hist[b] + atomicAdd(&cnt2[b], 1);
        if (r < CAP)
            rec[(size_t)b * CAP + r] =
                make_int2(all_t[e] | ((h & 63) << 18), __float_as_int(A[e]));
    }
}

// ---------------------------------------------------------------------------
// local_sort_k: per-bucket 64-bin counting sort in LDS -> h-grouped records
// + per-node (start,end) ranges.
// ---------------------------------------------------------------------------
__global__ __launch_bounds__(256)
void local_sort_k(const int* __restrict__ gcursor, int2* __restrict__ rec,
                  int2* __restrict__ range) {
    __shared__ int2 sin[CAP];
    __shared__ int2 sout[CAP];
    __shared__ int cnt64[64];
    __shared__ int pos64[64];
    int b = blockIdx.x, t = threadIdx.x;
    int cnt = gcursor[b]; if (cnt > CAP) cnt = CAP;

    if (t < 64) cnt64[t] = 0;
    __syncthreads();

    for (int i = t; i < cnt; i += 256) {
        int2 p = rec[(size_t)b * CAP + i];
        sin[i] = p;
        atomicAdd(&cnt64[(p.x >> 18) & 63], 1);
    }
    __syncthreads();

    if (t < 64) {
        int v = cnt64[t];
        int sum = v;
        #pragma unroll
        for (int off = 1; off < 64; off <<= 1) {
            int x = __shfl_up(sum, off, 64);
            if (t >= off) sum += x;
        }
        pos64[t] = sum - v;
    }
    __syncthreads();

    for (int i = t; i < cnt; i += 256) {
        int2 p = sin[i];
        int l = (p.x >> 18) & 63;
        int dst = atomicAdd(&pos64[l], 1);
        sout[dst] = make_int2(p.x & 0x3FFFF, p.y);
    }
    __syncthreads();

    for (int i = t; i < cnt; i += 256)
        rec[(size_t)b * CAP + i] = sout[i];

    if (t < 64) {
        int v = cnt64[t];
        int sum = v;
        #pragma unroll
        for (int off = 1; off < 64; off <<= 1) {
            int x = __shfl_up(sum, off, 64);
            if (t >= off) sum += x;
        }
        int start = b * CAP + (sum - v);
        int node = b * 64 + t;
        if (node < N_NODES) range[node] = make_int2(start, start + v);
    }
}

// ---------------------------------------------------------------------------
// side_k: wave-per-node segment-sum over bf16 rows.
// LPR = DIN/8 lanes cover one row (uint4 = 8 bf16 each); EPW = 64/LPR edges
// per wave-load. fp32 accumulate; cross-group shfl reduction; fp32 side out.
// ---------------------------------------------------------------------------
template<int DIN>
__global__ __launch_bounds__(256)
void side_k(const int2* __restrict__ range, const int2* __restrict__ rec,
            const unsigned short* __restrict__ tab, float* __restrict__ side) {
    constexpr int LPR = DIN / 8;       // 8 (D64), 4 (D32)
    constexpr int EPW = 64 / LPR;      // 8 (D64), 16 (D32)

    int w = threadIdx.x >> 6;
    int lane = threadIdx.x & 63;
    int h = blockIdx.x * 4 + w;

    int2 rg = range[h];
    int e0 = rg.x, e1 = rg.y;
    int g = lane / LPR;
    int q = lane % LPR;

    float acc[8];
    #pragma unroll
    for (int j = 0; j < 8; ++j) acc[j] = 0.f;

    for (int e = e0; e < e1; e += 2 * EPW) {
        int i0 = e + g;
        int i1 = e + EPW + g;
        int c0 = i0 < e1 ? i0 : e1 - 1;
        int c1 = i1 < e1 ? i1 : e1 - 1;
        int2 p0 = rec[c0];
        int2 p1 = rec[c1];
        float a0 = (i0 < e1) ? __int_as_float(p0.y) : 0.f;
        float a1 = (i1 < e1) ? __int_as_float(p1.y) : 0.f;
        uint4 d0 = *(const uint4*)(tab + (size_t)p0.x * DIN + q * 8);
        uint4 d1 = *(const uint4*)(tab + (size_t)p1.x * DIN + q * 8);
        acc[0] = fmaf(a0, bf_lo(d0.x), acc[0]);
        acc[1] = fmaf(a0, bf_hi(d0.x), acc[1]);
        acc[2] = fmaf(a0, bf_lo(d0.y), acc[2]);
        acc[3] = fmaf(a0, bf_hi(d0.y), acc[3]);
        acc[4] = fmaf(a0, bf_lo(d0.z), acc[4]);
        acc[5] = fmaf(a0, bf_hi(d0.z), acc[5]);
        acc[6] = fmaf(a0, bf_lo(d0.w), acc[6]);
        acc[7] = fmaf(a0, bf_hi(d0.w), acc[7]);
        acc[0] = fmaf(a1, bf_lo(d1.x), acc[0]);
        acc[1] = fmaf(a1, bf_hi(d1.x), acc[1]);
        acc[2] = fmaf(a1, bf_lo(d1.y), acc[2]);
        acc[3] = fmaf(a1, bf_hi(d1.y), acc[3]);
        acc[4] = fmaf(a1, bf_lo(d1.z), acc[4]);
        acc[5] = fmaf(a1, bf_hi(d1.z), acc[5]);
        acc[6] = fmaf(a1, bf_lo(d1.w), acc[6]);
        acc[7] = fmaf(a1, bf_hi(d1.w), acc[7]);
    }

    #pragma unroll
    for (int off = LPR; off < 64; off <<= 1)
        #pragma unroll
        for (int j = 0; j < 8; ++j) acc[j] += __shfl_xor(acc[j], off, 64);

    if (lane < LPR) {
        float* dst = side + (size_t)h * DIN + q * 8;
        *(float4*)dst       = make_float4(acc[0], acc[1], acc[2], acc[3]);
        *(float4*)(dst + 4) = make_float4(acc[4], acc[5], acc[6], acc[7]);
    }
}

// ---------------------------------------------------------------------------
// transform_k: tiled vector GEMM. ego_in is bf16 (or fp32 user/ent when
// CONCAT). Output bf16 (OUT_BF) or fp32.
// ---------------------------------------------------------------------------
template<int DIN, int DOUT, int TILE_ROWS, bool CONCAT, bool OUT_BF>
__global__ __launch_bounds__(256)
void transform_k(const unsigned short* __restrict__ ego_in,
                 const float* __restrict__ user_emb, const float* __restrict__ ent_emb,
                 const float* __restrict__ side,
                 const float* __restrict__ Wgc, const float* __restrict__ bgc,
                 const float* __restrict__ Wbi, const float* __restrict__ bbi,
                 void* __restrict__ ego_out) {
    constexpr int NG = DOUT / 8;
    constexpr int RG = 256 / NG;
    constexpr int RT = TILE_ROWS / RG;
    constexpr int STRIDE = DIN + 4;
    constexpr int KC8 = DIN / 8;

    __shared__ float sWgc[DIN * DOUT], sWbi[DIN * DOUT];
    __shared__ float sU[TILE_ROWS * STRIDE], sV[TILE_ROWS * STRIDE];

    int t = threadIdx.x;

    for (int i = t * 4; i < DIN * DOUT; i += 1024) {
        *(float4*)&sWgc[i] = *(const float4*)&Wgc[i];
        *(float4*)&sWbi[i] = *(const float4*)&Wbi[i];
    }

    int base = blockIdx.x * TILE_ROWS;
    for (int f = t; f < TILE_ROWS * KC8; f += 256) {
        int row = f / KC8, c8 = f % KC8;
        int n = base + row;
        int nc = n < N_NODES ? n : N_NODES - 1;
        float ev[8];
        if (CONCAT) {
            const float* erow = (nc < N_USERS) ? user_emb + (size_t)nc * 64
                                               : ent_emb + (size_t)(nc - N_USERS) * 64;
            float4 a = *(const float4*)(erow + c8 * 8);
            float4 b = *(const float4*)(erow + c8 * 8 + 4);
            ev[0] = a.x; ev[1] = a.y; ev[2] = a.z; ev[3] = a.w;
            ev[4] = b.x; ev[5] = b.y; ev[6] = b.z; ev[7] = b.w;
        } else {
            uint4 d = *(const uint4*)(ego_in + (size_t)nc * DIN + c8 * 8);
            ev[0] = bf_lo(d.x); ev[1] = bf_hi(d.x);
            ev[2] = bf_lo(d.y); ev[3] = bf_hi(d.y);
            ev[4] = bf_lo(d.z); ev[5] = bf_hi(d.z);
            ev[6] = bf_lo(d.w); ev[7] = bf_hi(d.w);
        }
        const float* srow = side + (size_t)nc * DIN + c8 * 8;
        float4 s0 = *(const float4*)srow;
        float4 s1 = *(const float4*)(srow + 4);
        float sv8[8] = {s0.x, s0.y, s0.z, s0.w, s1.x, s1.y, s1.z, s1.w};
        float* pu = &sU[row * STRIDE + c8 * 8];
        float* pv = &sV[row * STRIDE + c8 * 8];
        *(float4*)pu       = make_float4(ev[0] + sv8[0], ev[1] + sv8[1], ev[2] + sv8[2], ev[3] + sv8[3]);
        *(float4*)(pu + 4) = make_float4(ev[4] + sv8[4], ev[5] + sv8[5], ev[6] + sv8[6], ev[7] + sv8[7]);
        *(float4*)pv       = make_float4(ev[0] * sv8[0], ev[1] * sv8[1], ev[2] * sv8[2], ev[3] * sv8[3]);
        *(float4*)(pv + 4) = make_float4(ev[4] * sv8[4], ev[5] * sv8[5], ev[6] * sv8[6], ev[7] * sv8[7]);
    }
    __syncthreads();

    int cg = t % NG, rgi = t / NG;
    int c0 = cg * 8;
    int r0 = rgi * RT;

    float accg[RT][8], accb[RT][8];
    #pragma unroll
    for (int r = 0; r < RT; ++r)
        #pragma unroll
        for (int j = 0; j < 8; ++j) { accg[r][j] = 0.f; accb[r][j] = 0.f; }

    for (int k = 0; k < DIN; k += 4) {
        float4 u4[RT], v4[RT];
        #pragma unroll
        for (int r = 0; r < RT; ++r) {
            u4[r] = *(const float4*)&sU[(r0 + r) * STRIDE + k];
            v4[r] = *(const float4*)&sV[(r0 + r) * STRIDE + k];
        }
        #pragma unroll
        for (int kk = 0; kk < 4; ++kk) {
            float4 wg0 = *(const float4*)&sWgc[(k + kk) * DOUT + c0];
            float4 wg1 = *(const float4*)&sWgc[(k + kk) * DOUT + c0 + 4];
            float4 wb0 = *(const float4*)&sWbi[(k + kk) * DOUT + c0];
            float4 wb1 = *(const float4*)&sWbi[(k + kk) * DOUT + c0 + 4];
            #pragma unroll
            for (int r = 0; r < RT; ++r) {
                float u = ((const float*)&u4[r])[kk];
                float v = ((const float*)&v4[r])[kk];
                accg[r][0] = fmaf(u, wg0.x, accg[r][0]);
                accg[r][1] = fmaf(u, wg0.y, accg[r][1]);
                accg[r][2] = fmaf(u, wg0.z, accg[r][2]);
                accg[r][3] = fmaf(u, wg0.w, accg[r][3]);
                accg[r][4] = fmaf(u, wg1.x, accg[r][4]);
                accg[r][5] = fmaf(u, wg1.y, accg[r][5]);
                accg[r][6] = fmaf(u, wg1.z, accg[r][6]);
                accg[r][7] = fmaf(u, wg1.w, accg[r][7]);
                accb[r][0] = fmaf(v, wb0.x, accb[r][0]);
                accb[r][1] = fmaf(v, wb0.y, accb[r][1]);
                accb[r][2] = fmaf(v, wb0.z, accb[r][2]);
                accb[r][3] = fmaf(v, wb0.w, accb[r][3]);
                accb[r][4] = fmaf(v, wb1.x, accb[r][4]);
                accb[r][5] = fmaf(v, wb1.y, accb[r][5]);
                accb[r][6] = fmaf(v, wb1.z, accb[r][6]);
                accb[r][7] = fmaf(v, wb1.w, accb[r][7]);
            }
        }
    }

    float4 bg0 = *(const float4*)&bgc[c0];
    float4 bg1 = *(const float4*)&bgc[c0 + 4];
    float4 bb0 = *(const float4*)&bbi[c0];
    float4 bb1 = *(const float4*)&bbi[c0 + 4];
    float bg[8] = {bg0.x, bg0.y, bg0.z, bg0.w, bg1.x, bg1.y, bg1.z, bg1.w};
    float bb[8] = {bb0.x, bb0.y, bb0.z, bb0.w, bb1.x, bb1.y, bb1.z, bb1.w};

    #pragma unroll
    for (int r = 0; r < RT; ++r) {
        int n = base + r0 + r;
        if (n < N_NODES) {
            float o[8];
            #pragma unroll
            for (int j = 0; j < 8; ++j) {
                float gg = accg[r][j] + bg[j];
                float b2 = accb[r][j] + bb[j];
                gg = gg > 0.f ? gg : SLOPE * gg;
                b2 = b2 > 0.f ? b2 : SLOPE * b2;
                o[j] = gg + b2;
            }
            if (OUT_BF) {
                unsigned short* dst = (unsigned short*)ego_out + (size_t)n * DOUT + c0;
                uint4 wv;
                wv.x = f2bf(o[0]) | (f2bf(o[1]) << 16);
                wv.y = f2bf(o[2]) | (f2bf(o[3]) << 16);
                wv.z = f2bf(o[4]) | (f2bf(o[5]) << 16);
                wv.w = f2bf(o[6]) | (f2bf(o[7]) << 16);
                *(uint4*)dst = wv;
            } else {
                float* dst = (float*)ego_out + (size_t)n * DOUT + c0;
                *(float4*)dst       = make_float4(o[0], o[1], o[2], o[3]);
                *(float4*)(dst + 4) = make_float4(o[4], o[5], o[6], o[7]);
            }
        }
    }
}

// ---------------------------------------------------------------------------
// Gather: out rows = [ego0(64) | norm(ego1)(64) | norm(ego2)(32) | norm(ego3)(16)]
// ---------------------------------------------------------------------------
__global__ __launch_bounds__(64)
void gather_k(const int* __restrict__ users, const int* __restrict__ pos,
              const int* __restrict__ neg,
              const float* __restrict__ user_emb, const float* __restrict__ ent_emb,
              const unsigned short* __restrict__ ego1_bf,
              const unsigned short* __restrict__ ego2_bf,
              const float* __restrict__ ego3,
              float* __restrict__ out) {
    int r = blockIdx.x;
    int lane = threadIdx.x;
    int which = r / BATCH;
    int i = r - which * BATCH;
    int node;
    if (which == 0)      node = users[i];
    else if (which == 1) node = N_USERS + pos[i];
    else                 node = N_USERS + neg[i];

    float* o = out + (size_t)r * 176;

    float x0 = (node < N_USERS) ? user_emb[(size_t)node * 64 + lane]
                                : ent_emb[(size_t)(node - N_USERS) * 64 + lane];
    o[lane] = x0;

    float x1 = __uint_as_float((unsigned)ego1_bf[(size_t)node * 64 + lane] << 16);
    float ss = x1 * x1;
    #pragma unroll
    for (int off = 32; off > 0; off >>= 1) ss += __shfl_xor(ss, off, 64);
    o[64 + lane] = x1 / fmaxf(sqrtf(ss), EPSF);

    float x2 = (lane < 32)
        ? __uint_as_float((unsigned)ego2_bf[(size_t)node * 32 + lane] << 16) : 0.f;
    float ss2 = x2 * x2;
    #pragma unroll
    for (int off = 32; off > 0; off >>= 1) ss2 += __shfl_xor(ss2, off, 64);
    if (lane < 32) o[128 + lane] = x2 / fmaxf(sqrtf(ss2), EPSF);

    float x3 = (lane < 16) ? ego3[(size_t)node * 16 + lane] : 0.f;
    float ss3 = x3 * x3;
    #pragma unroll
    for (int off = 32; off > 0; off >>= 1) ss3 += __shfl_xor(ss3, off, 64);
    if (lane < 16) o[160 + lane] = x3 / fmaxf(sqrtf(ss3), EPSF);
}

// ---------------------------------------------------------------------------
extern "C" void kernel_launch(void* const* d_in, const int* in_sizes, int n_in,
                              void* d_out, int out_size, void* d_ws, size_t ws_size,
                              hipStream_t stream) {
    const int*   users    = (const int*)d_in[0];
    const int*   pos      = (const int*)d_in[1];
    const int*   neg      = (const int*)d_in[2];
    const int*   all_h    = (const int*)d_in[3];
    const int*   all_t    = (const int*)d_in[4];
    const float* A        = (const float*)d_in[5];
    const float* user_emb = (const float*)d_in[6];
    const float* ent_emb  = (const float*)d_in[7];
    const float* Wgc0 = (const float*)d_in[8];
    const float* bgc0 = (const float*)d_in[9];
    const float* Wbi0 = (const float*)d_in[10];
    const float* bbi0 = (const float*)d_in[11];
    const float* Wgc1 = (const float*)d_in[12];
    const float* bgc1 = (const float*)d_in[13];
    const float* Wbi1 = (const float*)d_in[14];
    const float* bbi1 = (const float*)d_in[15];
    const float* Wgc2 = (const float*)d_in[16];
    const float* bgc2 = (const float*)d_in[17];
    const float* Wbi2 = (const float*)d_in[18];
    const float* bbi2 = (const float*)d_in[19];

    // ---- workspace (256B-aligned). rec dead after side L2 -> ego3 aliases.
    char* p = (char*)d_ws;
    int*   gcursor = (int*)p;            p += ((size_t)NBUK * 4 + 255) & ~255ull;
    int2*  rec     = (int2*)p;           char* rec_base = p;
    p += ((size_t)NBUK * CAP * 8 + 255) & ~255ull;
    int2*  range   = (int2*)p;           p += ((size_t)N_NODES * 8 + 255) & ~255ull;
    float* side    = (float*)p;          p += ((size_t)N_NODES * 64 * 4 + 255) & ~255ull;
    unsigned short* ego0_bf = (unsigned short*)p; p += ((size_t)N_NODES * 64 * 2 + 255) & ~255ull;
    unsigned short* ego1_bf = (unsigned short*)p; p += ((size_t)N_NODES * 64 * 2 + 255) & ~255ull;
    unsigned short* ego2_bf = (unsigned short*)p; p += ((size_t)N_NODES * 32 * 2 + 255) & ~255ull;
    float* ego3    = (float*)rec_base;   // aliases rec (dead by then)
    float* out     = (float*)d_out;

    const int nodeBlocks = N_NODES / 4;

    // ---- prep: bf16 concat table + bucket partition + local sort ----
    (void)hipMemsetAsync(gcursor, 0, (size_t)NBUK * 4, stream);
    cast0_k<<<(N_NODES * 64 / 4 + 255) / 256, 256, 0, stream>>>(user_emb, ent_emb, ego0_bf);
    partition_k<<<NPB, PBLK, 0, stream>>>(all_h, all_t, A, gcursor, rec);
    local_sort_k<<<NBUK, 256, 0, stream>>>(gcursor, rec, range);

    // ---- layer 0: 64 -> 64 ----
    side_k<64><<<nodeBlocks, 256, 0, stream>>>(range, rec, ego0_bf, side);
    transform_k<64, 64, 64, true, true><<<(N_NODES + 63) / 64, 256, 0, stream>>>(
        nullptr, user_emb, ent_emb, side, Wgc0, bgc0, Wbi0, bbi0, ego1_bf);

    // ---- layer 1: 64 -> 32 ----
    side_k<64><<<nodeBlocks, 256, 0, stream>>>(range, rec, ego1_bf, side);
    transform_k<64, 32, 64, false, true><<<(N_NODES + 63) / 64, 256, 0, stream>>>(
        ego1_bf, nullptr, nullptr, side, Wgc1, bgc1, Wbi1, bbi1, ego2_bf);

    // ---- layer 2: 32 -> 16 ----
    side_k<32><<<nodeBlocks, 256, 0, stream>>>(range, rec, ego2_bf, side);
    transform_k<32, 16, 128, false, false><<<(N_NODES + 127) / 128, 256, 0, stream>>>(
        ego2_bf, nullptr, nullptr, side, Wgc2, bgc2, Wbi2, bbi2, ego3);

    // ---- final gather + lazy normalization ----
    gather_k<<<3 * BATCH, 64, 0, stream>>>(
        users, pos, neg, user_emb, ent_emb, ego1_bf, ego2_bf, ego3, out);
}